// Round 1
// baseline (4357.048 us; speedup 1.0000x reference)
//
#include <hip/hip_runtime.h>
#include <math.h>

// EnhancedTransformerBlock on MI355X — Round 1: correct fp32 baseline.
// Decomposition:
//   gemm(x,Wq)+bq -> q ; gemm(x,Wk)+bk -> k ; gemm(x,Wv)+bv -> v
//   flash attention (online softmax) -> ctx
//   gemm(ctx,Wo)+bo+x -> ao ; adaLN1(ao) -> x1
//   gelu(gemm(x1,ffn_w1)+b1) -> h ; gemm(h,ffn_w2)+b2 -> ffn
//   relu(gemm(x1,gate_w1)+gb1) -> gh ; sigmoid(gemm(gh,gate_w2)+gb2) -> g
//   adaLN2( x1*(2-g) + ffn*g ) -> out
// Workspace peak: 6*T*H floats = 192 MiB (regions reused across phases).

#define HDIM 1024      // hidden size
#define NHEAD 16
#define DHEAD 64       // head dim
#define NBATCH 8
#define NSEQ 1024
#define NTOK (NBATCH * NSEQ)   // 8192
#define LNEPS 1e-5f

enum { ACT_NONE = 0, ACT_GELU = 1, ACT_RELU = 2, ACT_SIG = 3 };

// ---------------------------------------------------------------------------
// Generic fp32 GEMM: C[M,N] = act(A[M,K] @ W[K,N] + bias[N] (+ add[M,N]))
// 128x128 tile, BK=16, 256 threads, 8x8 microtile. All dims multiples of 128/16.
// ---------------------------------------------------------------------------
template<int ACT, bool HAS_ADD>
__global__ __launch_bounds__(256)
void gemm_k(const float* __restrict__ A, const float* __restrict__ W,
            const float* __restrict__ bias, const float* __restrict__ add,
            float* __restrict__ C, int M, int N, int K)
{
    __shared__ float As[16][128];   // [k][m]
    __shared__ float Ws[16][128];   // [k][n]
    const int tid = threadIdx.x;
    const int tx = tid & 15;        // n-dir
    const int ty = tid >> 4;        // m-dir
    const int m0 = blockIdx.y * 128;
    const int n0 = blockIdx.x * 128;

    float acc[8][8];
#pragma unroll
    for (int i = 0; i < 8; ++i)
#pragma unroll
        for (int j = 0; j < 8; ++j) acc[i][j] = 0.f;

    for (int k0 = 0; k0 < K; k0 += 16) {
        __syncthreads();
#pragma unroll
        for (int r = 0; r < 8; ++r) {
            int li = tid + r * 256;
            int m = li >> 4, k = li & 15;
            As[k][m] = A[(size_t)(m0 + m) * K + (k0 + k)];
        }
#pragma unroll
        for (int r = 0; r < 8; ++r) {
            int li = tid + r * 256;
            int k = li >> 7, n = li & 127;
            Ws[k][n] = W[(size_t)(k0 + k) * N + (n0 + n)];
        }
        __syncthreads();
#pragma unroll
        for (int kk = 0; kk < 16; ++kk) {
            float am[8], wn[8];
#pragma unroll
            for (int i = 0; i < 8; ++i) am[i] = As[kk][ty * 8 + i];
#pragma unroll
            for (int j = 0; j < 8; ++j) wn[j] = Ws[kk][tx * 8 + j];
#pragma unroll
            for (int i = 0; i < 8; ++i)
#pragma unroll
                for (int j = 0; j < 8; ++j)
                    acc[i][j] = fmaf(am[i], wn[j], acc[i][j]);
        }
    }

#pragma unroll
    for (int i = 0; i < 8; ++i) {
        const int m = m0 + ty * 8 + i;
        const int nb = n0 + tx * 8;
        float v[8];
#pragma unroll
        for (int j = 0; j < 8; ++j) {
            float t = acc[i][j] + bias[nb + j];
            if (HAS_ADD) t += add[(size_t)m * N + nb + j];
            if (ACT == ACT_GELU)      t = 0.5f * t * (1.f + erff(t * 0.70710678118654752f));
            else if (ACT == ACT_RELU) t = fmaxf(t, 0.f);
            else if (ACT == ACT_SIG)  t = 1.f / (1.f + __expf(-t));
            v[j] = t;
        }
        float4* cp = (float4*)&C[(size_t)m * N + nb];
        cp[0] = make_float4(v[0], v[1], v[2], v[3]);
        cp[1] = make_float4(v[4], v[5], v[6], v[7]);
    }
}

// ---------------------------------------------------------------------------
// Flash-style attention, fp32. One thread = one query row; K/V tiles 64x64
// staged in LDS; per-key online softmax (scale 1/8 folded into Q).
// grid = (NSEQ/256, NHEAD, NBATCH), block = 256.
// ---------------------------------------------------------------------------
__global__ __launch_bounds__(256)
void attn_k(const float* __restrict__ Q, const float* __restrict__ Kv,
            const float* __restrict__ Vv, float* __restrict__ ctx)
{
    __shared__ float Ks[64][64];
    __shared__ float Vs[64][64];
    const int tid = threadIdx.x;
    const int b = blockIdx.z;
    const int h = blockIdx.y;
    const int s = blockIdx.x * 256 + tid;
    const size_t qoff = ((size_t)(b * NSEQ + s)) * HDIM + h * DHEAD;

    float qreg[64], o[64];
#pragma unroll
    for (int d = 0; d < 64; d += 4) {
        float4 t4 = *(const float4*)&Q[qoff + d];
        qreg[d]     = t4.x * 0.125f;
        qreg[d + 1] = t4.y * 0.125f;
        qreg[d + 2] = t4.z * 0.125f;
        qreg[d + 3] = t4.w * 0.125f;
        o[d] = o[d + 1] = o[d + 2] = o[d + 3] = 0.f;
    }
    float m = -1e30f, l = 0.f;

    for (int kt = 0; kt < NSEQ / 64; ++kt) {
        __syncthreads();
#pragma unroll
        for (int r = 0; r < 4; ++r) {
            int li = tid + r * 256;            // float4 units over 64x16
            int row = li >> 4, c = (li & 15) * 4;
            size_t goff = ((size_t)(b * NSEQ + kt * 64 + row)) * HDIM + h * DHEAD + c;
            *(float4*)&Ks[row][c] = *(const float4*)&Kv[goff];
            *(float4*)&Vs[row][c] = *(const float4*)&Vv[goff];
        }
        __syncthreads();
#pragma unroll 1
        for (int kk = 0; kk < 64; ++kk) {
            float sc = 0.f;
#pragma unroll
            for (int d = 0; d < 64; ++d) sc = fmaf(qreg[d], Ks[kk][d], sc);
            float mnew = fmaxf(m, sc);
            float corr = __expf(m - mnew);
            float p = __expf(sc - mnew);
            l = l * corr + p;
#pragma unroll
            for (int d = 0; d < 64; ++d) o[d] = fmaf(o[d], corr, p * Vs[kk][d]);
            m = mnew;
        }
    }
    const float rl = 1.f / l;
#pragma unroll
    for (int d = 0; d < 64; d += 4)
        *(float4*)&ctx[qoff + d] =
            make_float4(o[d] * rl, o[d + 1] * rl, o[d + 2] * rl, o[d + 3] * rl);
}

// ---------------------------------------------------------------------------
// ada-LayerNorm. MODE 0: y_in = a.  MODE 1: y_in = a*(2-g) + fo*g
// out = LN(y_in)*(1+sigmoid(vol*vsw+vsb))*gamma + beta
// grid = NTOK blocks, 256 threads (4 elems/thread).
// ---------------------------------------------------------------------------
template<int MODE>
__global__ __launch_bounds__(256)
void adaln_k(const float* __restrict__ a, const float* __restrict__ fo,
             const float* __restrict__ g, const float* __restrict__ vol,
             const float* __restrict__ lw, const float* __restrict__ lb,
             const float* __restrict__ gm, const float* __restrict__ bt,
             const float* __restrict__ vsw, const float* __restrict__ vsb,
             float* __restrict__ out)
{
    const int tok = blockIdx.x;
    const int tid = threadIdx.x;
    const size_t base = (size_t)tok * HDIM + tid * 4;
    float v[4];
    {
        float4 va = *(const float4*)&a[base];
        if (MODE == 1) {
            float4 vf = *(const float4*)&fo[base];
            float4 vg = *(const float4*)&g[base];
            v[0] = va.x * (2.f - vg.x) + vf.x * vg.x;
            v[1] = va.y * (2.f - vg.y) + vf.y * vg.y;
            v[2] = va.z * (2.f - vg.z) + vf.z * vg.z;
            v[3] = va.w * (2.f - vg.w) + vf.w * vg.w;
        } else {
            v[0] = va.x; v[1] = va.y; v[2] = va.z; v[3] = va.w;
        }
    }
    float sum = v[0] + v[1] + v[2] + v[3];
    float sq  = v[0]*v[0] + v[1]*v[1] + v[2]*v[2] + v[3]*v[3];
#pragma unroll
    for (int off = 32; off > 0; off >>= 1) {
        sum += __shfl_down(sum, off);
        sq  += __shfl_down(sq, off);
    }
    __shared__ float ssum[4], ssq[4];
    const int wid = tid >> 6, lane = tid & 63;
    if (lane == 0) { ssum[wid] = sum; ssq[wid] = sq; }
    __syncthreads();
    const float tsum = ssum[0] + ssum[1] + ssum[2] + ssum[3];
    const float tsq  = ssq[0]  + ssq[1]  + ssq[2]  + ssq[3];
    const float mu   = tsum * (1.f / 1024.f);
    const float var  = tsq * (1.f / 1024.f) - mu * mu;
    const float rstd = rsqrtf(var + LNEPS);
    const float vsv  = 1.f / (1.f + __expf(-(vol[tok] * vsw[0] + vsb[0])));
    const float sca  = (1.f + vsv) * gm[0];
    const float off2 = bt[0];
    const float4 lwv = *(const float4*)&lw[tid * 4];
    const float4 lbv = *(const float4*)&lb[tid * 4];
    float r0 = ((v[0] - mu) * rstd * lwv.x + lbv.x) * sca + off2;
    float r1 = ((v[1] - mu) * rstd * lwv.y + lbv.y) * sca + off2;
    float r2 = ((v[2] - mu) * rstd * lwv.z + lbv.z) * sca + off2;
    float r3 = ((v[3] - mu) * rstd * lwv.w + lbv.w) * sca + off2;
    *(float4*)&out[base] = make_float4(r0, r1, r2, r3);
}

// ---------------------------------------------------------------------------
extern "C" void kernel_launch(void* const* d_in, const int* in_sizes, int n_in,
                              void* d_out, int out_size, void* d_ws, size_t ws_size,
                              hipStream_t stream)
{
    (void)in_sizes; (void)n_in; (void)out_size; (void)ws_size;
    const float* x    = (const float*)d_in[0];
    const float* vol  = (const float*)d_in[1];
    const float* Wq   = (const float*)d_in[2];  const float* bq  = (const float*)d_in[3];
    const float* Wk   = (const float*)d_in[4];  const float* bk  = (const float*)d_in[5];
    const float* Wv   = (const float*)d_in[6];  const float* bv  = (const float*)d_in[7];
    const float* Wo   = (const float*)d_in[8];  const float* bo  = (const float*)d_in[9];
    const float* ln1w = (const float*)d_in[10]; const float* ln1b = (const float*)d_in[11];
    const float* gm1  = (const float*)d_in[12]; const float* be1 = (const float*)d_in[13];
    const float* vs1w = (const float*)d_in[14]; const float* vs1b = (const float*)d_in[15];
    const float* fw1  = (const float*)d_in[16]; const float* fb1 = (const float*)d_in[17];
    const float* fw2  = (const float*)d_in[18]; const float* fb2 = (const float*)d_in[19];
    const float* gw1  = (const float*)d_in[20]; const float* gb1 = (const float*)d_in[21];
    const float* gw2  = (const float*)d_in[22]; const float* gb2 = (const float*)d_in[23];
    const float* ln2w = (const float*)d_in[24]; const float* ln2b = (const float*)d_in[25];
    const float* gm2  = (const float*)d_in[26]; const float* be2 = (const float*)d_in[27];
    const float* vs2w = (const float*)d_in[28]; const float* vs2b = (const float*)d_in[29];

    float* ws = (float*)d_ws;
    const size_t TH = (size_t)NTOK * HDIM;   // 8M floats = 32 MiB
    // Phase 1 regions:
    float* q    = ws + 0 * TH;
    float* kb   = ws + 1 * TH;
    float* vb   = ws + 2 * TH;
    float* cx   = ws + 3 * TH;
    float* ao   = ws + 4 * TH;
    float* x1   = ws + 5 * TH;   // live until the end
    // Phase 2 reuse (q..cx dead after Wo gemm; ao dead after adaLN1):
    float* hbuf = ws + 0 * TH;   // 4*TH (T x 4096)
    float* ffn  = ws + 4 * TH;   // TH
    // Phase 3 reuse (hbuf dead after ffn2 gemm):
    float* gh   = ws + 0 * TH;   // TH/2 (T x 512)
    float* gg   = ws + 1 * TH;   // TH
    // peak = 6*TH floats = 192 MiB <= ws_size (harness scratch)

    dim3 blk(256);
    gemm_k<ACT_NONE, false><<<dim3(HDIM / 128, NTOK / 128), blk, 0, stream>>>(
        x, Wq, bq, nullptr, q, NTOK, HDIM, HDIM);
    gemm_k<ACT_NONE, false><<<dim3(HDIM / 128, NTOK / 128), blk, 0, stream>>>(
        x, Wk, bk, nullptr, kb, NTOK, HDIM, HDIM);
    gemm_k<ACT_NONE, false><<<dim3(HDIM / 128, NTOK / 128), blk, 0, stream>>>(
        x, Wv, bv, nullptr, vb, NTOK, HDIM, HDIM);
    attn_k<<<dim3(NSEQ / 256, NHEAD, NBATCH), blk, 0, stream>>>(q, kb, vb, cx);
    gemm_k<ACT_NONE, true><<<dim3(HDIM / 128, NTOK / 128), blk, 0, stream>>>(
        cx, Wo, bo, x, ao, NTOK, HDIM, HDIM);
    adaln_k<0><<<dim3(NTOK), blk, 0, stream>>>(
        ao, nullptr, nullptr, vol, ln1w, ln1b, gm1, be1, vs1w, vs1b, x1);
    gemm_k<ACT_GELU, false><<<dim3(4096 / 128, NTOK / 128), blk, 0, stream>>>(
        x1, fw1, fb1, nullptr, hbuf, NTOK, 4096, HDIM);
    gemm_k<ACT_NONE, false><<<dim3(HDIM / 128, NTOK / 128), blk, 0, stream>>>(
        hbuf, fw2, fb2, nullptr, ffn, NTOK, HDIM, 4096);
    gemm_k<ACT_RELU, false><<<dim3(512 / 128, NTOK / 128), blk, 0, stream>>>(
        x1, gw1, gb1, nullptr, gh, NTOK, 512, HDIM);
    gemm_k<ACT_SIG, false><<<dim3(HDIM / 128, NTOK / 128), blk, 0, stream>>>(
        gh, gw2, gb2, nullptr, gg, NTOK, HDIM, 512);
    adaln_k<1><<<dim3(NTOK), blk, 0, stream>>>(
        x1, ffn, gg, vol, ln2w, ln2b, gm2, be2, vs2w, vs2b, (float*)d_out);
}

// Round 2
// 1443.896 us; speedup vs baseline: 3.0176x; 3.0176x over previous
//
#include <hip/hip_runtime.h>
#include <hip/hip_bf16.h>
#include <math.h>

// EnhancedTransformerBlock on MI355X — Round 2: bf16 MFMA GEMMs + spill-free attention.
// GEMMs: 128x128 tile, BK=32, 4 waves, mfma_f32_16x16x32_bf16, global_load_lds(16B).
// Weights transposed+cast to [N,K] bf16 in ws so A and B fragment reads are both
// contiguous-K ds_read_b128. Attention: fp32 flash, 4 threads/row (16 d each).

#define HDIM 1024
#define NHEAD 16
#define DHEAD 64
#define NBATCH 8
#define NSEQ 1024
#define NTOK (NBATCH * NSEQ)   // 8192
#define LNEPS 1e-5f

using f32x4 = __attribute__((ext_vector_type(4))) float;
using s16x8 = __attribute__((ext_vector_type(8))) short;
using u16x8 = __attribute__((ext_vector_type(8))) unsigned short;

enum { ACT_NONE = 0, ACT_GELU = 1, ACT_RELU = 2, ACT_SIG = 3 };

__device__ inline float bf2f(unsigned short u) {
    union { unsigned u; float f; } t; t.u = ((unsigned)u) << 16; return t.f;
}
__device__ inline unsigned short f2bf(float f) {
    __hip_bfloat16 h = __float2bfloat16(f);
    return *reinterpret_cast<unsigned short*>(&h);
}

// ---------------------------------------------------------------------------
// fp32 -> bf16 cast (vectorized), n4 = count of float4s
// ---------------------------------------------------------------------------
__global__ __launch_bounds__(256)
void cast_bf16_k(const float* __restrict__ in, unsigned short* __restrict__ out, int n4)
{
    for (int i = blockIdx.x * 256 + threadIdx.x; i < n4; i += gridDim.x * 256) {
        float4 v = ((const float4*)in)[i];
        ushort4 o;
        o.x = f2bf(v.x); o.y = f2bf(v.y); o.z = f2bf(v.z); o.w = f2bf(v.w);
        ((ushort4*)out)[i] = o;
    }
}

// ---------------------------------------------------------------------------
// W[K,N] fp32 -> Wt[N,K] bf16 (32x32 LDS tile transpose), block (32,8)
// ---------------------------------------------------------------------------
__global__ __launch_bounds__(256)
void transpose_cast_k(const float* __restrict__ W, unsigned short* __restrict__ Wt,
                      int K, int N)
{
    __shared__ float tile[32][33];
    const int tx = threadIdx.x, ty = threadIdx.y;
    const int k0 = blockIdx.y * 32, n0 = blockIdx.x * 32;
#pragma unroll
    for (int r = 0; r < 32; r += 8)
        tile[ty + r][tx] = W[(size_t)(k0 + ty + r) * N + n0 + tx];
    __syncthreads();
#pragma unroll
    for (int r = 0; r < 32; r += 8)
        Wt[(size_t)(n0 + ty + r) * K + k0 + tx] = f2bf(tile[tx][ty + r]);
}

// ---------------------------------------------------------------------------
// bf16 MFMA GEMM: C[M,N] = act(A[M,K] @ B[K,N] + bias (+ add)), B given as Bt[N,K].
// 128x128 tile, BK=32, 256 threads (4 waves 2x2), 4x4 16x16 fragments per wave.
// ---------------------------------------------------------------------------
#define GLDS16(g, l) __builtin_amdgcn_global_load_lds( \
    (__attribute__((address_space(1))) void*)(g),      \
    (__attribute__((address_space(3))) void*)(l), 16, 0, 0)

template<int ACT, bool HAS_ADD, bool OUT_BF>
__global__ __launch_bounds__(256)
void gemm_k(const unsigned short* __restrict__ A,   // [M,K] bf16
            const unsigned short* __restrict__ Bt,  // [N,K] bf16
            const float* __restrict__ bias,         // [N]
            const float* __restrict__ add,          // [M,N] fp32 (HAS_ADD)
            void* __restrict__ Cv, int M, int N, int K)
{
    __shared__ alignas(16) unsigned short As[128 * 32];
    __shared__ alignas(16) unsigned short Bs[128 * 32];
    const int tid = threadIdx.x;
    const int lane = tid & 63;
    const int wid = tid >> 6;
    const int wm = (wid >> 1) * 64;
    const int wn = (wid & 1) * 64;
    const int m0 = blockIdx.y * 128;
    const int n0 = blockIdx.x * 128;

    const int srow = lane >> 2;        // row within 16-row chunk
    const int skc = (lane & 3) * 8;    // k element offset of this lane's 16B

    f32x4 acc[4][4] = {};

    for (int k0 = 0; k0 < K; k0 += 32) {
        __syncthreads();
#pragma unroll
        for (int j = 0; j < 2; ++j) {
            const int chunk = wid * 2 + j;           // 0..7, wave-uniform
            const int row = chunk * 16 + srow;       // 0..127
            GLDS16(A  + (size_t)(m0 + row) * K + k0 + skc, As + chunk * 512);
            GLDS16(Bt + (size_t)(n0 + row) * K + k0 + skc, Bs + chunk * 512);
        }
        __syncthreads();   // drains vmcnt -> LDS tiles valid

        s16x8 af[4], bfr[4];
        const int fr = lane & 15;
        const int fk = (lane >> 4) * 8;
#pragma unroll
        for (int i = 0; i < 4; ++i) {
            af[i]  = *(const s16x8*)(As + (wm + i * 16 + fr) * 32 + fk);
            bfr[i] = *(const s16x8*)(Bs + (wn + i * 16 + fr) * 32 + fk);
        }
#pragma unroll
        for (int i = 0; i < 4; ++i)
#pragma unroll
            for (int j = 0; j < 4; ++j)
                acc[i][j] = __builtin_amdgcn_mfma_f32_16x16x32_bf16(
                    af[i], bfr[j], acc[i][j], 0, 0, 0);
    }

    const int col = lane & 15;
    const int rbase = (lane >> 4) * 4;
#pragma unroll
    for (int i = 0; i < 4; ++i) {
#pragma unroll
        for (int j = 0; j < 4; ++j) {
            const int gn = n0 + wn + j * 16 + col;
            const float bv = bias[gn];
#pragma unroll
            for (int r = 0; r < 4; ++r) {
                const int gm = m0 + wm + i * 16 + rbase + r;
                float t = acc[i][j][r] + bv;
                if (HAS_ADD) t += add[(size_t)gm * N + gn];
                if (ACT == ACT_GELU)      t = 0.5f * t * (1.f + erff(t * 0.70710678118654752f));
                else if (ACT == ACT_RELU) t = fmaxf(t, 0.f);
                else if (ACT == ACT_SIG)  t = 1.f / (1.f + __expf(-t));
                if (OUT_BF) ((unsigned short*)Cv)[(size_t)gm * N + gn] = f2bf(t);
                else        ((float*)Cv)[(size_t)gm * N + gn] = t;
            }
        }
    }
}

// ---------------------------------------------------------------------------
// fp32 flash attention, bf16 inputs/outputs. 4 threads per query row (16 d each),
// K/V tiles 64x64 staged fp32 in LDS (pad 68), online softmax.
// grid = (NSEQ/64, NHEAD, NBATCH), block = 256.
// ---------------------------------------------------------------------------
__global__ __launch_bounds__(256)
void attn_k(const unsigned short* __restrict__ Qb, const unsigned short* __restrict__ Kb,
            const unsigned short* __restrict__ Vb, unsigned short* __restrict__ Cb)
{
    __shared__ float Ks[64][68];
    __shared__ float Vs[64][68];
    const int tid = threadIdx.x;
    const int r = tid >> 2;
    const int seg = tid & 3;
    const int b = blockIdx.z, h = blockIdx.y;
    const int s = blockIdx.x * 64 + r;
    const size_t qoff = ((size_t)(b * NSEQ + s)) * HDIM + h * DHEAD + seg * 16;

    float4 q4[4];
    {
        u16x8 a = *(const u16x8*)(Qb + qoff);
        u16x8 c = *(const u16x8*)(Qb + qoff + 8);
        q4[0] = make_float4(bf2f(a[0]) * 0.125f, bf2f(a[1]) * 0.125f,
                            bf2f(a[2]) * 0.125f, bf2f(a[3]) * 0.125f);
        q4[1] = make_float4(bf2f(a[4]) * 0.125f, bf2f(a[5]) * 0.125f,
                            bf2f(a[6]) * 0.125f, bf2f(a[7]) * 0.125f);
        q4[2] = make_float4(bf2f(c[0]) * 0.125f, bf2f(c[1]) * 0.125f,
                            bf2f(c[2]) * 0.125f, bf2f(c[3]) * 0.125f);
        q4[3] = make_float4(bf2f(c[4]) * 0.125f, bf2f(c[5]) * 0.125f,
                            bf2f(c[6]) * 0.125f, bf2f(c[7]) * 0.125f);
    }
    float4 o0 = make_float4(0, 0, 0, 0), o1 = o0, o2 = o0, o3 = o0;
    float m = -1e30f, l = 0.f;

    const int srow = tid >> 2;
    const int scol = (tid & 3) * 16;

    for (int kt = 0; kt < NSEQ / 64; ++kt) {
        __syncthreads();
        {
            const size_t goff = ((size_t)(b * NSEQ + kt * 64 + srow)) * HDIM + h * DHEAD + scol;
            u16x8 ka = *(const u16x8*)(Kb + goff), kc = *(const u16x8*)(Kb + goff + 8);
            u16x8 va = *(const u16x8*)(Vb + goff), vc = *(const u16x8*)(Vb + goff + 8);
            float* kd = &Ks[srow][scol];
            float* vd = &Vs[srow][scol];
            *(float4*)(kd + 0)  = make_float4(bf2f(ka[0]), bf2f(ka[1]), bf2f(ka[2]), bf2f(ka[3]));
            *(float4*)(kd + 4)  = make_float4(bf2f(ka[4]), bf2f(ka[5]), bf2f(ka[6]), bf2f(ka[7]));
            *(float4*)(kd + 8)  = make_float4(bf2f(kc[0]), bf2f(kc[1]), bf2f(kc[2]), bf2f(kc[3]));
            *(float4*)(kd + 12) = make_float4(bf2f(kc[4]), bf2f(kc[5]), bf2f(kc[6]), bf2f(kc[7]));
            *(float4*)(vd + 0)  = make_float4(bf2f(va[0]), bf2f(va[1]), bf2f(va[2]), bf2f(va[3]));
            *(float4*)(vd + 4)  = make_float4(bf2f(va[4]), bf2f(va[5]), bf2f(va[6]), bf2f(va[7]));
            *(float4*)(vd + 8)  = make_float4(bf2f(vc[0]), bf2f(vc[1]), bf2f(vc[2]), bf2f(vc[3]));
            *(float4*)(vd + 12) = make_float4(bf2f(vc[4]), bf2f(vc[5]), bf2f(vc[6]), bf2f(vc[7]));
        }
        __syncthreads();

#pragma unroll 4
        for (int kk = 0; kk < 64; ++kk) {
            const float4* kr = (const float4*)&Ks[kk][seg * 16];
            float4 ck0 = kr[0], ck1 = kr[1], ck2 = kr[2], ck3 = kr[3];
            float s0 = fmaf(q4[0].x, ck0.x, fmaf(q4[0].y, ck0.y, fmaf(q4[0].z, ck0.z, q4[0].w * ck0.w)));
            float s1 = fmaf(q4[1].x, ck1.x, fmaf(q4[1].y, ck1.y, fmaf(q4[1].z, ck1.z, q4[1].w * ck1.w)));
            float s2 = fmaf(q4[2].x, ck2.x, fmaf(q4[2].y, ck2.y, fmaf(q4[2].z, ck2.z, q4[2].w * ck2.w)));
            float s3 = fmaf(q4[3].x, ck3.x, fmaf(q4[3].y, ck3.y, fmaf(q4[3].z, ck3.z, q4[3].w * ck3.w)));
            float sc = (s0 + s1) + (s2 + s3);
            sc += __shfl_xor(sc, 1);
            sc += __shfl_xor(sc, 2);
            const float mnew = fmaxf(m, sc);
            const float corr = __expf(m - mnew);
            const float p = __expf(sc - mnew);
            l = fmaf(l, corr, p);
            const float4* vr = (const float4*)&Vs[kk][seg * 16];
            float4 cv0 = vr[0], cv1 = vr[1], cv2 = vr[2], cv3 = vr[3];
            o0.x = fmaf(o0.x, corr, p * cv0.x); o0.y = fmaf(o0.y, corr, p * cv0.y);
            o0.z = fmaf(o0.z, corr, p * cv0.z); o0.w = fmaf(o0.w, corr, p * cv0.w);
            o1.x = fmaf(o1.x, corr, p * cv1.x); o1.y = fmaf(o1.y, corr, p * cv1.y);
            o1.z = fmaf(o1.z, corr, p * cv1.z); o1.w = fmaf(o1.w, corr, p * cv1.w);
            o2.x = fmaf(o2.x, corr, p * cv2.x); o2.y = fmaf(o2.y, corr, p * cv2.y);
            o2.z = fmaf(o2.z, corr, p * cv2.z); o2.w = fmaf(o2.w, corr, p * cv2.w);
            o3.x = fmaf(o3.x, corr, p * cv3.x); o3.y = fmaf(o3.y, corr, p * cv3.y);
            o3.z = fmaf(o3.z, corr, p * cv3.z); o3.w = fmaf(o3.w, corr, p * cv3.w);
            m = mnew;
        }
    }
    const float rl = 1.f / l;
    u16x8 w0, w1;
    w0[0] = f2bf(o0.x * rl); w0[1] = f2bf(o0.y * rl); w0[2] = f2bf(o0.z * rl); w0[3] = f2bf(o0.w * rl);
    w0[4] = f2bf(o1.x * rl); w0[5] = f2bf(o1.y * rl); w0[6] = f2bf(o1.z * rl); w0[7] = f2bf(o1.w * rl);
    w1[0] = f2bf(o2.x * rl); w1[1] = f2bf(o2.y * rl); w1[2] = f2bf(o2.z * rl); w1[3] = f2bf(o2.w * rl);
    w1[4] = f2bf(o3.x * rl); w1[5] = f2bf(o3.y * rl); w1[6] = f2bf(o3.z * rl); w1[7] = f2bf(o3.w * rl);
    *(u16x8*)(Cb + qoff) = w0;
    *(u16x8*)(Cb + qoff + 8) = w1;
}

// ---------------------------------------------------------------------------
// ada-LayerNorm. MODE 0: y = a (also writes bf16 copy). MODE 1: y = a*(2-g)+fo*g.
// ---------------------------------------------------------------------------
template<int MODE, bool WRITE_BF>
__global__ __launch_bounds__(256)
void adaln_k(const float* __restrict__ a, const float* __restrict__ fo,
             const float* __restrict__ g, const float* __restrict__ vol,
             const float* __restrict__ lw, const float* __restrict__ lb,
             const float* __restrict__ gm, const float* __restrict__ bt,
             const float* __restrict__ vsw, const float* __restrict__ vsb,
             float* __restrict__ out, unsigned short* __restrict__ out_bf)
{
    const int tok = blockIdx.x;
    const int tid = threadIdx.x;
    const size_t base = (size_t)tok * HDIM + tid * 4;
    float v[4];
    {
        float4 va = *(const float4*)&a[base];
        if (MODE == 1) {
            float4 vf = *(const float4*)&fo[base];
            float4 vg = *(const float4*)&g[base];
            v[0] = va.x * (2.f - vg.x) + vf.x * vg.x;
            v[1] = va.y * (2.f - vg.y) + vf.y * vg.y;
            v[2] = va.z * (2.f - vg.z) + vf.z * vg.z;
            v[3] = va.w * (2.f - vg.w) + vf.w * vg.w;
        } else {
            v[0] = va.x; v[1] = va.y; v[2] = va.z; v[3] = va.w;
        }
    }
    float sum = v[0] + v[1] + v[2] + v[3];
    float sq  = v[0]*v[0] + v[1]*v[1] + v[2]*v[2] + v[3]*v[3];
#pragma unroll
    for (int off = 32; off > 0; off >>= 1) {
        sum += __shfl_down(sum, off);
        sq  += __shfl_down(sq, off);
    }
    __shared__ float ssum[4], ssq[4];
    const int wid = tid >> 6, lane = tid & 63;
    if (lane == 0) { ssum[wid] = sum; ssq[wid] = sq; }
    __syncthreads();
    const float tsum = ssum[0] + ssum[1] + ssum[2] + ssum[3];
    const float tsq  = ssq[0]  + ssq[1]  + ssq[2]  + ssq[3];
    const float mu   = tsum * (1.f / 1024.f);
    const float var  = tsq * (1.f / 1024.f) - mu * mu;
    const float rstd = rsqrtf(var + LNEPS);
    const float vsv  = 1.f / (1.f + __expf(-(vol[tok] * vsw[0] + vsb[0])));
    const float sca  = (1.f + vsv) * gm[0];
    const float off2 = bt[0];
    const float4 lwv = *(const float4*)&lw[tid * 4];
    const float4 lbv = *(const float4*)&lb[tid * 4];
    float r0 = ((v[0] - mu) * rstd * lwv.x + lbv.x) * sca + off2;
    float r1 = ((v[1] - mu) * rstd * lwv.y + lbv.y) * sca + off2;
    float r2 = ((v[2] - mu) * rstd * lwv.z + lbv.z) * sca + off2;
    float r3 = ((v[3] - mu) * rstd * lwv.w + lbv.w) * sca + off2;
    *(float4*)&out[base] = make_float4(r0, r1, r2, r3);
    if (WRITE_BF) {
        ushort4 ob;
        ob.x = f2bf(r0); ob.y = f2bf(r1); ob.z = f2bf(r2); ob.w = f2bf(r3);
        *(ushort4*)&out_bf[base] = ob;
    }
}

// ---------------------------------------------------------------------------
extern "C" void kernel_launch(void* const* d_in, const int* in_sizes, int n_in,
                              void* d_out, int out_size, void* d_ws, size_t ws_size,
                              hipStream_t stream)
{
    (void)in_sizes; (void)n_in; (void)out_size; (void)ws_size;
    const float* x    = (const float*)d_in[0];
    const float* vol  = (const float*)d_in[1];
    const float* Wq   = (const float*)d_in[2];  const float* bq  = (const float*)d_in[3];
    const float* Wk   = (const float*)d_in[4];  const float* bk  = (const float*)d_in[5];
    const float* Wv   = (const float*)d_in[6];  const float* bv  = (const float*)d_in[7];
    const float* Wo   = (const float*)d_in[8];  const float* bo  = (const float*)d_in[9];
    const float* ln1w = (const float*)d_in[10]; const float* ln1b = (const float*)d_in[11];
    const float* gm1  = (const float*)d_in[12]; const float* be1 = (const float*)d_in[13];
    const float* vs1w = (const float*)d_in[14]; const float* vs1b = (const float*)d_in[15];
    const float* fw1  = (const float*)d_in[16]; const float* fb1 = (const float*)d_in[17];
    const float* fw2  = (const float*)d_in[18]; const float* fb2 = (const float*)d_in[19];
    const float* gw1  = (const float*)d_in[20]; const float* gb1 = (const float*)d_in[21];
    const float* gw2  = (const float*)d_in[22]; const float* gb2 = (const float*)d_in[23];
    const float* ln2w = (const float*)d_in[24]; const float* ln2b = (const float*)d_in[25];
    const float* gm2  = (const float*)d_in[26]; const float* be2 = (const float*)d_in[27];
    const float* vs2w = (const float*)d_in[28]; const float* vs2b = (const float*)d_in[29];

    char* w = (char*)d_ws;
    auto MB = [](size_t v) { return v << 20; };
    // transposed bf16 weights (live whole call): 26 MiB
    unsigned short* wtq  = (unsigned short*)(w + MB(0));
    unsigned short* wtk  = (unsigned short*)(w + MB(2));
    unsigned short* wtv  = (unsigned short*)(w + MB(4));
    unsigned short* wto  = (unsigned short*)(w + MB(6));
    unsigned short* wtf1 = (unsigned short*)(w + MB(8));   // [4096,1024]
    unsigned short* wtf2 = (unsigned short*)(w + MB(16));  // [1024,4096]
    unsigned short* wtg1 = (unsigned short*)(w + MB(24));  // [512,1024]
    unsigned short* wtg2 = (unsigned short*)(w + MB(25));  // [1024,512]
    // activations (byte offsets; regions reused once dead):
    unsigned short* xb  = (unsigned short*)(w + MB(26));   // [1-3]
    unsigned short* qb  = (unsigned short*)(w + MB(42));   // [3-4]
    unsigned short* kb  = (unsigned short*)(w + MB(58));   // [3-4]
    unsigned short* vb  = (unsigned short*)(w + MB(74));   // [3-4]
    unsigned short* cxb = (unsigned short*)(w + MB(90));   // [4-5]
    float*          ao  = (float*)(w + MB(106));           // [5-6]
    float*          x1  = (float*)(w + MB(138));           // [6-end]
    unsigned short* x1b = (unsigned short*)(w + MB(170));  // [6-10]
    unsigned short* hb  = (unsigned short*)(w + MB(42));   // [7-8]  reuse qb..cxb (64 MiB)
    float*          ffn = (float*)(w + MB(106));           // [8-end] reuse ao
    unsigned short* ghb = (unsigned short*)(w + MB(26));   // [9-10] reuse xb
    float*          gg  = (float*)(w + MB(42));            // [10-end] reuse hb
    // peak footprint: 186 MiB

    dim3 blk(256);
    dim3 tb(32, 8);
    transpose_cast_k<<<dim3(1024/32, 1024/32), tb, 0, stream>>>(Wq, wtq, 1024, 1024);
    transpose_cast_k<<<dim3(1024/32, 1024/32), tb, 0, stream>>>(Wk, wtk, 1024, 1024);
    transpose_cast_k<<<dim3(1024/32, 1024/32), tb, 0, stream>>>(Wv, wtv, 1024, 1024);
    transpose_cast_k<<<dim3(1024/32, 1024/32), tb, 0, stream>>>(Wo, wto, 1024, 1024);
    transpose_cast_k<<<dim3(4096/32, 1024/32), tb, 0, stream>>>(fw1, wtf1, 1024, 4096);
    transpose_cast_k<<<dim3(1024/32, 4096/32), tb, 0, stream>>>(fw2, wtf2, 4096, 1024);
    transpose_cast_k<<<dim3(512/32, 1024/32),  tb, 0, stream>>>(gw1, wtg1, 1024, 512);
    transpose_cast_k<<<dim3(1024/32, 512/32),  tb, 0, stream>>>(gw2, wtg2, 512, 1024);
    cast_bf16_k<<<2048, blk, 0, stream>>>(x, xb, NTOK * HDIM / 4);

    gemm_k<ACT_NONE, false, true><<<dim3(8, 64), blk, 0, stream>>>(
        xb, wtq, bq, nullptr, qb, NTOK, HDIM, HDIM);
    gemm_k<ACT_NONE, false, true><<<dim3(8, 64), blk, 0, stream>>>(
        xb, wtk, bk, nullptr, kb, NTOK, HDIM, HDIM);
    gemm_k<ACT_NONE, false, true><<<dim3(8, 64), blk, 0, stream>>>(
        xb, wtv, bv, nullptr, vb, NTOK, HDIM, HDIM);
    attn_k<<<dim3(NSEQ / 64, NHEAD, NBATCH), blk, 0, stream>>>(qb, kb, vb, cxb);
    gemm_k<ACT_NONE, true, false><<<dim3(8, 64), blk, 0, stream>>>(
        cxb, wto, bo, x, ao, NTOK, HDIM, HDIM);
    adaln_k<0, true><<<dim3(NTOK), blk, 0, stream>>>(
        ao, nullptr, nullptr, vol, ln1w, ln1b, gm1, be1, vs1w, vs1b, x1, x1b);
    gemm_k<ACT_GELU, false, true><<<dim3(32, 64), blk, 0, stream>>>(
        x1b, wtf1, fb1, nullptr, hb, NTOK, 4096, HDIM);
    gemm_k<ACT_NONE, false, false><<<dim3(8, 64), blk, 0, stream>>>(
        hb, wtf2, fb2, nullptr, ffn, NTOK, HDIM, 4096);
    gemm_k<ACT_RELU, false, true><<<dim3(4, 64), blk, 0, stream>>>(
        x1b, wtg1, gb1, nullptr, ghb, NTOK, 512, HDIM);
    gemm_k<ACT_SIG, false, false><<<dim3(8, 64), blk, 0, stream>>>(
        ghb, wtg2, gb2, nullptr, gg, NTOK, HDIM, 512);
    adaln_k<1, false><<<dim3(NTOK), blk, 0, stream>>>(
        x1, ffn, gg, vol, ln2w, ln2b, gm2, be2, vs2w, vs2b, (float*)d_out, nullptr);
}

// Round 4
// 603.822 us; speedup vs baseline: 7.2158x; 2.3913x over previous
//
#include <hip/hip_runtime.h>
#include <hip/hip_bf16.h>
#include <math.h>

// EnhancedTransformerBlock on MI355X — Round 4: MFMA flash attention (round-3
// plus the missing adaln_k argument fix).
// GEMMs unchanged from round 2 (128x128, BK=32, mfma 16x16x32 bf16, global_load_lds).
// Attention: per block = (b,h) x 64 q-rows, 4 waves x 16 rows. K and V^T tiles
// staged via global_load_lds with row-XOR swizzle (pre-swizzled source, rule #21).
// QK^T and PV on MFMA; online softmax in exp2 domain; P repacked via padded
// per-wave LDS buffer.

#define HDIM 1024
#define NHEAD 16
#define DHEAD 64
#define NBATCH 8
#define NSEQ 1024
#define NTOK (NBATCH * NSEQ)   // 8192
#define LNEPS 1e-5f
#define LOG2E_8 0.180336880f   // log2(e)/8

using f32x4 = __attribute__((ext_vector_type(4))) float;
using s16x8 = __attribute__((ext_vector_type(8))) short;
using u16x8 = __attribute__((ext_vector_type(8))) unsigned short;

enum { ACT_NONE = 0, ACT_GELU = 1, ACT_RELU = 2, ACT_SIG = 3 };

__device__ inline float bf2f(unsigned short u) {
    union { unsigned u; float f; } t; t.u = ((unsigned)u) << 16; return t.f;
}
__device__ inline unsigned short f2bf(float f) {
    __hip_bfloat16 h = __float2bfloat16(f);
    return *reinterpret_cast<unsigned short*>(&h);
}

#define GLDS16(g, l) __builtin_amdgcn_global_load_lds( \
    (__attribute__((address_space(1))) void*)(g),      \
    (__attribute__((address_space(3))) void*)(l), 16, 0, 0)

// ---------------------------------------------------------------------------
// fp32 -> bf16 cast (vectorized), n4 = count of float4s
// ---------------------------------------------------------------------------
__global__ __launch_bounds__(256)
void cast_bf16_k(const float* __restrict__ in, unsigned short* __restrict__ out, int n4)
{
    for (int i = blockIdx.x * 256 + threadIdx.x; i < n4; i += gridDim.x * 256) {
        float4 v = ((const float4*)in)[i];
        ushort4 o;
        o.x = f2bf(v.x); o.y = f2bf(v.y); o.z = f2bf(v.z); o.w = f2bf(v.w);
        ((ushort4*)out)[i] = o;
    }
}

// ---------------------------------------------------------------------------
// W[K,N] fp32 -> Wt[N,K] bf16 (32x32 LDS tile transpose), block (32,8)
// ---------------------------------------------------------------------------
__global__ __launch_bounds__(256)
void transpose_cast_k(const float* __restrict__ W, unsigned short* __restrict__ Wt,
                      int K, int N)
{
    __shared__ float tile[32][33];
    const int tx = threadIdx.x, ty = threadIdx.y;
    const int k0 = blockIdx.y * 32, n0 = blockIdx.x * 32;
#pragma unroll
    for (int r = 0; r < 32; r += 8)
        tile[ty + r][tx] = W[(size_t)(k0 + ty + r) * N + n0 + tx];
    __syncthreads();
#pragma unroll
    for (int r = 0; r < 32; r += 8)
        Wt[(size_t)(n0 + ty + r) * K + k0 + tx] = f2bf(tile[tx][ty + r]);
}

// ---------------------------------------------------------------------------
// V[b*S+s][h*64+d] bf16 -> Vt[(b*NHEAD+h)*64+d][s] bf16. Per block: 64x64 tile.
// ---------------------------------------------------------------------------
__global__ __launch_bounds__(256)
void transpose_v_k(const unsigned short* __restrict__ vb, unsigned short* __restrict__ vtb)
{
    __shared__ unsigned short t[64][72];   // 144B row stride (16B-aligned)
    const int tid = threadIdx.x;
    const int b = blockIdx.z, h = blockIdx.y;
    const int s0 = blockIdx.x * 64;
    {
        const int r = tid >> 3, c = (tid & 7) * 8;
        *(u16x8*)&t[r][c] =
            *(const u16x8*)&vb[((size_t)(b * NSEQ + s0 + r)) * HDIM + h * DHEAD + c];
        *(u16x8*)&t[r + 32][c] =
            *(const u16x8*)&vb[((size_t)(b * NSEQ + s0 + r + 32)) * HDIM + h * DHEAD + c];
    }
    __syncthreads();
    {
        const int d = tid & 63, sc = (tid >> 6) * 16;
        u16x8 o0, o1;
#pragma unroll
        for (int i = 0; i < 8; ++i) o0[i] = t[sc + i][d];
#pragma unroll
        for (int i = 0; i < 8; ++i) o1[i] = t[sc + 8 + i][d];
        unsigned short* dst = &vtb[((size_t)((b * NHEAD + h) * DHEAD + d)) * NSEQ + s0 + sc];
        *(u16x8*)dst = o0;
        *(u16x8*)(dst + 8) = o1;
    }
}

// ---------------------------------------------------------------------------
// bf16 MFMA GEMM (round-2 structure, unchanged)
// ---------------------------------------------------------------------------
template<int ACT, bool HAS_ADD, bool OUT_BF>
__global__ __launch_bounds__(256)
void gemm_k(const unsigned short* __restrict__ A,   // [M,K] bf16
            const unsigned short* __restrict__ Bt,  // [N,K] bf16
            const float* __restrict__ bias,         // [N]
            const float* __restrict__ add,          // [M,N] fp32 (HAS_ADD)
            void* __restrict__ Cv, int M, int N, int K)
{
    __shared__ alignas(16) unsigned short As[128 * 32];
    __shared__ alignas(16) unsigned short Bs[128 * 32];
    const int tid = threadIdx.x;
    const int lane = tid & 63;
    const int wid = tid >> 6;
    const int wm = (wid >> 1) * 64;
    const int wn = (wid & 1) * 64;
    const int m0 = blockIdx.y * 128;
    const int n0 = blockIdx.x * 128;

    const int srow = lane >> 2;
    const int skc = (lane & 3) * 8;

    f32x4 acc[4][4] = {};

    for (int k0 = 0; k0 < K; k0 += 32) {
        __syncthreads();
#pragma unroll
        for (int j = 0; j < 2; ++j) {
            const int chunk = wid * 2 + j;
            const int row = chunk * 16 + srow;
            GLDS16(A  + (size_t)(m0 + row) * K + k0 + skc, As + chunk * 512);
            GLDS16(Bt + (size_t)(n0 + row) * K + k0 + skc, Bs + chunk * 512);
        }
        __syncthreads();

        s16x8 af[4], bfr[4];
        const int fr = lane & 15;
        const int fk = (lane >> 4) * 8;
#pragma unroll
        for (int i = 0; i < 4; ++i) {
            af[i]  = *(const s16x8*)(As + (wm + i * 16 + fr) * 32 + fk);
            bfr[i] = *(const s16x8*)(Bs + (wn + i * 16 + fr) * 32 + fk);
        }
#pragma unroll
        for (int i = 0; i < 4; ++i)
#pragma unroll
            for (int j = 0; j < 4; ++j)
                acc[i][j] = __builtin_amdgcn_mfma_f32_16x16x32_bf16(
                    af[i], bfr[j], acc[i][j], 0, 0, 0);
    }

    const int col = lane & 15;
    const int rbase = (lane >> 4) * 4;
#pragma unroll
    for (int i = 0; i < 4; ++i) {
#pragma unroll
        for (int j = 0; j < 4; ++j) {
            const int gn = n0 + wn + j * 16 + col;
            const float bv = bias[gn];
#pragma unroll
            for (int r = 0; r < 4; ++r) {
                const int gm = m0 + wm + i * 16 + rbase + r;
                float t = acc[i][j][r] + bv;
                if (HAS_ADD) t += add[(size_t)gm * N + gn];
                if (ACT == ACT_GELU)      t = 0.5f * t * (1.f + erff(t * 0.70710678118654752f));
                else if (ACT == ACT_RELU) t = fmaxf(t, 0.f);
                else if (ACT == ACT_SIG)  t = 1.f / (1.f + __expf(-t));
                if (OUT_BF) ((unsigned short*)Cv)[(size_t)gm * N + gn] = f2bf(t);
                else        ((float*)Cv)[(size_t)gm * N + gn] = t;
            }
        }
    }
}

// ---------------------------------------------------------------------------
// MFMA flash attention. Block = (qtile, h, b); 4 waves x 16 q-rows.
// K tile [64 keys][64 d] and Vt tile [64 d][64 keys] in LDS, XOR-swizzled rows
// (byte ^= (row&7)<<4) realized by pre-swizzling the global_load_lds source.
// ---------------------------------------------------------------------------
__global__ __launch_bounds__(256)
void attn_k(const unsigned short* __restrict__ Qb, const unsigned short* __restrict__ Kb,
            const unsigned short* __restrict__ Vtb, unsigned short* __restrict__ Cb)
{
    __shared__ alignas(16) unsigned short Ks[64 * 64];
    __shared__ alignas(16) unsigned short Vs[64 * 64];
    __shared__ alignas(16) unsigned short Ps[4][16 * 72];

    const int tid = threadIdx.x;
    const int lane = tid & 63;
    const int wid = tid >> 6;
    const int b = blockIdx.z, h = blockIdx.y;
    const int q0 = blockIdx.x * 64 + wid * 16;

    // Q A-fragments: row = lane&15, k(d) = (lane>>4)*8 (+32 for second half)
    const int kcol = lane & 15;
    const int kofs = (lane >> 4) * 8;
    const size_t qoff = ((size_t)(b * NSEQ + q0 + kcol)) * HDIM + h * DHEAD + kofs;
    const s16x8 qf0 = *(const s16x8*)(Qb + qoff);
    const s16x8 qf1 = *(const s16x8*)(Qb + qoff + 32);

    f32x4 accO[4] = {};
    float mrow[4] = {-1e30f, -1e30f, -1e30f, -1e30f};
    float lrow[4] = {0.f, 0.f, 0.f, 0.f};

    // staging source decomposition: lane covers 16B of row (8*wid + 8j + lane>>3)
    const int lr = lane >> 3;                       // 0..7
    const int swz8 = (((lane & 7) ^ lr)) * 8;       // pre-swizzled element offset
    const size_t kbase  = ((size_t)(b * NSEQ)) * HDIM + h * DHEAD;
    const size_t vtbase = ((size_t)((b * NHEAD + h) * DHEAD)) * NSEQ;

    unsigned short* const pw = &Ps[wid][0];
    const int prow = (lane >> 4) * 4;

    for (int kt = 0; kt < NSEQ / 64; ++kt) {
        __syncthreads();
#pragma unroll
        for (int j = 0; j < 2; ++j) {
            const int rowb = wid * 16 + j * 8;      // wave-uniform
            GLDS16(Kb + kbase + (size_t)(kt * 64 + rowb + lr) * HDIM + swz8,
                   Ks + rowb * 64);
            GLDS16(Vtb + vtbase + (size_t)(rowb + lr) * NSEQ + kt * 64 + swz8,
                   Vs + rowb * 64);
        }
        __syncthreads();

        // ---- QK^T: S[16q x 64k] per wave
        f32x4 sa[4];
#pragma unroll
        for (int jt = 0; jt < 4; ++jt) {
            const int kr = jt * 16 + kcol;
            const unsigned swz = ((unsigned)(kr & 7)) << 4;
            const s16x8 kf0 = *(const s16x8*)((const char*)Ks + kr * 128 + ((kofs * 2) ^ swz));
            const s16x8 kf1 = *(const s16x8*)((const char*)Ks + kr * 128 + ((64 + kofs * 2) ^ swz));
            f32x4 t = {};
            t = __builtin_amdgcn_mfma_f32_16x16x32_bf16(qf0, kf0, t, 0, 0, 0);
            t = __builtin_amdgcn_mfma_f32_16x16x32_bf16(qf1, kf1, t, 0, 0, 0);
            sa[jt] = t * LOG2E_8;   // exp2 domain, 1/8 scale folded
        }

        // ---- online softmax (rows live in 16-lane groups)
        float p[4][4];
        float corr[4];
#pragma unroll
        for (int r = 0; r < 4; ++r) {
            float mx = fmaxf(fmaxf(sa[0][r], sa[1][r]), fmaxf(sa[2][r], sa[3][r]));
            mx = fmaxf(mx, __shfl_xor(mx, 1));
            mx = fmaxf(mx, __shfl_xor(mx, 2));
            mx = fmaxf(mx, __shfl_xor(mx, 4));
            mx = fmaxf(mx, __shfl_xor(mx, 8));
            const float mn = fmaxf(mrow[r], mx);
            corr[r] = exp2f(mrow[r] - mn);
            mrow[r] = mn;
            float ps = 0.f;
#pragma unroll
            for (int jt = 0; jt < 4; ++jt) {
                p[jt][r] = exp2f(sa[jt][r] - mn);
                ps += p[jt][r];
            }
            ps += __shfl_xor(ps, 1);
            ps += __shfl_xor(ps, 2);
            ps += __shfl_xor(ps, 4);
            ps += __shfl_xor(ps, 8);
            lrow[r] = lrow[r] * corr[r] + ps;
        }

        // ---- P -> per-wave LDS (bf16), padded stride 72
#pragma unroll
        for (int r = 0; r < 4; ++r)
#pragma unroll
            for (int jt = 0; jt < 4; ++jt)
                pw[(prow + r) * 72 + jt * 16 + kcol] = f2bf(p[jt][r]);

        // ---- rescale O
#pragma unroll
        for (int dt = 0; dt < 4; ++dt)
#pragma unroll
            for (int r = 0; r < 4; ++r)
                accO[dt][r] *= corr[r];

        // ---- PV: O[16q x 64d] += P[16q x 64k] * V[64k x 64d]
#pragma unroll
        for (int kc = 0; kc < 2; ++kc) {
            const s16x8 pa = *(const s16x8*)(pw + kcol * 72 + kc * 32 + kofs);
#pragma unroll
            for (int dt = 0; dt < 4; ++dt) {
                const int dr = dt * 16 + kcol;
                const unsigned swz = ((unsigned)(dr & 7)) << 4;
                const s16x8 vf = *(const s16x8*)((const char*)Vs + dr * 128 +
                                                 ((kc * 64 + kofs * 2) ^ swz));
                accO[dt] = __builtin_amdgcn_mfma_f32_16x16x32_bf16(pa, vf, accO[dt], 0, 0, 0);
            }
        }
    }

    // ---- epilogue: O /= l, write bf16
    const size_t obase = ((size_t)(b * NSEQ + q0 + prow)) * HDIM + h * DHEAD;
#pragma unroll
    for (int r = 0; r < 4; ++r) {
        const float rl = 1.f / lrow[r];
#pragma unroll
        for (int dt = 0; dt < 4; ++dt)
            Cb[obase + (size_t)r * HDIM + dt * 16 + kcol] = f2bf(accO[dt][r] * rl);
    }
}

// ---------------------------------------------------------------------------
// ada-LayerNorm (round-2, unchanged)
// ---------------------------------------------------------------------------
template<int MODE, bool WRITE_BF>
__global__ __launch_bounds__(256)
void adaln_k(const float* __restrict__ a, const float* __restrict__ fo,
             const float* __restrict__ g, const float* __restrict__ vol,
             const float* __restrict__ lw, const float* __restrict__ lb,
             const float* __restrict__ gm, const float* __restrict__ bt,
             const float* __restrict__ vsw, const float* __restrict__ vsb,
             float* __restrict__ out, unsigned short* __restrict__ out_bf)
{
    const int tok = blockIdx.x;
    const int tid = threadIdx.x;
    const size_t base = (size_t)tok * HDIM + tid * 4;
    float v[4];
    {
        float4 va = *(const float4*)&a[base];
        if (MODE == 1) {
            float4 vf = *(const float4*)&fo[base];
            float4 vg = *(const float4*)&g[base];
            v[0] = va.x * (2.f - vg.x) + vf.x * vg.x;
            v[1] = va.y * (2.f - vg.y) + vf.y * vg.y;
            v[2] = va.z * (2.f - vg.z) + vf.z * vg.z;
            v[3] = va.w * (2.f - vg.w) + vf.w * vg.w;
        } else {
            v[0] = va.x; v[1] = va.y; v[2] = va.z; v[3] = va.w;
        }
    }
    float sum = v[0] + v[1] + v[2] + v[3];
    float sq  = v[0]*v[0] + v[1]*v[1] + v[2]*v[2] + v[3]*v[3];
#pragma unroll
    for (int off = 32; off > 0; off >>= 1) {
        sum += __shfl_down(sum, off);
        sq  += __shfl_down(sq, off);
    }
    __shared__ float ssum[4], ssq[4];
    const int wid = tid >> 6, lane = tid & 63;
    if (lane == 0) { ssum[wid] = sum; ssq[wid] = sq; }
    __syncthreads();
    const float tsum = ssum[0] + ssum[1] + ssum[2] + ssum[3];
    const float tsq  = ssq[0]  + ssq[1]  + ssq[2]  + ssq[3];
    const float mu   = tsum * (1.f / 1024.f);
    const float var  = tsq * (1.f / 1024.f) - mu * mu;
    const float rstd = rsqrtf(var + LNEPS);
    const float vsv  = 1.f / (1.f + __expf(-(vol[tok] * vsw[0] + vsb[0])));
    const float sca  = (1.f + vsv) * gm[0];
    const float off2 = bt[0];
    const float4 lwv = *(const float4*)&lw[tid * 4];
    const float4 lbv = *(const float4*)&lb[tid * 4];
    float r0 = ((v[0] - mu) * rstd * lwv.x + lbv.x) * sca + off2;
    float r1 = ((v[1] - mu) * rstd * lwv.y + lbv.y) * sca + off2;
    float r2 = ((v[2] - mu) * rstd * lwv.z + lbv.z) * sca + off2;
    float r3 = ((v[3] - mu) * rstd * lwv.w + lbv.w) * sca + off2;
    *(float4*)&out[base] = make_float4(r0, r1, r2, r3);
    if (WRITE_BF) {
        ushort4 ob;
        ob.x = f2bf(r0); ob.y = f2bf(r1); ob.z = f2bf(r2); ob.w = f2bf(r3);
        *(ushort4*)&out_bf[base] = ob;
    }
}

// ---------------------------------------------------------------------------
extern "C" void kernel_launch(void* const* d_in, const int* in_sizes, int n_in,
                              void* d_out, int out_size, void* d_ws, size_t ws_size,
                              hipStream_t stream)
{
    (void)in_sizes; (void)n_in; (void)out_size; (void)ws_size;
    const float* x    = (const float*)d_in[0];
    const float* vol  = (const float*)d_in[1];
    const float* Wq   = (const float*)d_in[2];  const float* bq  = (const float*)d_in[3];
    const float* Wk   = (const float*)d_in[4];  const float* bk  = (const float*)d_in[5];
    const float* Wv   = (const float*)d_in[6];  const float* bv  = (const float*)d_in[7];
    const float* Wo   = (const float*)d_in[8];  const float* bo  = (const float*)d_in[9];
    const float* ln1w = (const float*)d_in[10]; const float* ln1b = (const float*)d_in[11];
    const float* gm1  = (const float*)d_in[12]; const float* be1 = (const float*)d_in[13];
    const float* vs1w = (const float*)d_in[14]; const float* vs1b = (const float*)d_in[15];
    const float* fw1  = (const float*)d_in[16]; const float* fb1 = (const float*)d_in[17];
    const float* fw2  = (const float*)d_in[18]; const float* fb2 = (const float*)d_in[19];
    const float* gw1  = (const float*)d_in[20]; const float* gb1 = (const float*)d_in[21];
    const float* gw2  = (const float*)d_in[22]; const float* gb2 = (const float*)d_in[23];
    const float* ln2w = (const float*)d_in[24]; const float* ln2b = (const float*)d_in[25];
    const float* gm2  = (const float*)d_in[26]; const float* be2 = (const float*)d_in[27];
    const float* vs2w = (const float*)d_in[28]; const float* vs2b = (const float*)d_in[29];

    char* w = (char*)d_ws;
    auto MB = [](size_t v) { return v << 20; };
    unsigned short* wtq  = (unsigned short*)(w + MB(0));
    unsigned short* wtk  = (unsigned short*)(w + MB(2));
    unsigned short* wtv  = (unsigned short*)(w + MB(4));
    unsigned short* wto  = (unsigned short*)(w + MB(6));
    unsigned short* wtf1 = (unsigned short*)(w + MB(8));
    unsigned short* wtf2 = (unsigned short*)(w + MB(16));
    unsigned short* wtg1 = (unsigned short*)(w + MB(24));
    unsigned short* wtg2 = (unsigned short*)(w + MB(25));
    unsigned short* xb  = (unsigned short*)(w + MB(26));
    unsigned short* qb  = (unsigned short*)(w + MB(42));
    unsigned short* kb  = (unsigned short*)(w + MB(58));
    unsigned short* vb  = (unsigned short*)(w + MB(74));
    unsigned short* cxb = (unsigned short*)(w + MB(90));
    float*          ao  = (float*)(w + MB(106));
    unsigned short* vtb = (unsigned short*)(w + MB(106));  // lives only during attn; ao written after
    float*          x1  = (float*)(w + MB(138));
    unsigned short* x1b = (unsigned short*)(w + MB(170));
    unsigned short* hb  = (unsigned short*)(w + MB(42));
    float*          ffn = (float*)(w + MB(106));
    unsigned short* ghb = (unsigned short*)(w + MB(26));
    float*          gg  = (float*)(w + MB(42));

    dim3 blk(256);
    dim3 tb(32, 8);
    transpose_cast_k<<<dim3(1024/32, 1024/32), tb, 0, stream>>>(Wq, wtq, 1024, 1024);
    transpose_cast_k<<<dim3(1024/32, 1024/32), tb, 0, stream>>>(Wk, wtk, 1024, 1024);
    transpose_cast_k<<<dim3(1024/32, 1024/32), tb, 0, stream>>>(Wv, wtv, 1024, 1024);
    transpose_cast_k<<<dim3(1024/32, 1024/32), tb, 0, stream>>>(Wo, wto, 1024, 1024);
    transpose_cast_k<<<dim3(4096/32, 1024/32), tb, 0, stream>>>(fw1, wtf1, 1024, 4096);
    transpose_cast_k<<<dim3(1024/32, 4096/32), tb, 0, stream>>>(fw2, wtf2, 4096, 1024);
    transpose_cast_k<<<dim3(512/32, 1024/32),  tb, 0, stream>>>(gw1, wtg1, 1024, 512);
    transpose_cast_k<<<dim3(1024/32, 512/32),  tb, 0, stream>>>(gw2, wtg2, 512, 1024);
    cast_bf16_k<<<2048, blk, 0, stream>>>(x, xb, NTOK * HDIM / 4);

    gemm_k<ACT_NONE, false, true><<<dim3(8, 64), blk, 0, stream>>>(
        xb, wtq, bq, nullptr, qb, NTOK, HDIM, HDIM);
    gemm_k<ACT_NONE, false, true><<<dim3(8, 64), blk, 0, stream>>>(
        xb, wtk, bk, nullptr, kb, NTOK, HDIM, HDIM);
    gemm_k<ACT_NONE, false, true><<<dim3(8, 64), blk, 0, stream>>>(
        xb, wtv, bv, nullptr, vb, NTOK, HDIM, HDIM);
    transpose_v_k<<<dim3(NSEQ / 64, NHEAD, NBATCH), blk, 0, stream>>>(vb, vtb);
    attn_k<<<dim3(NSEQ / 64, NHEAD, NBATCH), blk, 0, stream>>>(qb, kb, vtb, cxb);
    gemm_k<ACT_NONE, true, false><<<dim3(8, 64), blk, 0, stream>>>(
        cxb, wto, bo, x, ao, NTOK, HDIM, HDIM);
    adaln_k<0, true><<<dim3(NTOK), blk, 0, stream>>>(
        ao, nullptr, nullptr, vol, ln1w, ln1b, gm1, be1, vs1w, vs1b, x1, x1b);
    gemm_k<ACT_GELU, false, true><<<dim3(32, 64), blk, 0, stream>>>(
        x1b, wtf1, fb1, nullptr, hb, NTOK, 4096, HDIM);
    gemm_k<ACT_NONE, false, false><<<dim3(8, 64), blk, 0, stream>>>(
        hb, wtf2, fb2, nullptr, ffn, NTOK, HDIM, 4096);
    gemm_k<ACT_RELU, false, true><<<dim3(4, 64), blk, 0, stream>>>(
        x1b, wtg1, gb1, nullptr, ghb, NTOK, 512, HDIM);
    gemm_k<ACT_SIG, false, false><<<dim3(8, 64), blk, 0, stream>>>(
        ghb, wtg2, gb2, nullptr, gg, NTOK, HDIM, 512);
    adaln_k<1, false><<<dim3(NTOK), blk, 0, stream>>>(
        x1, ffn, gg, vol, ln2w, ln2b, gm2, be2, vs2w, vs2b, (float*)d_out, nullptr);
}

// Round 5
// 525.065 us; speedup vs baseline: 8.2981x; 1.1500x over previous
//
#include <hip/hip_runtime.h>
#include <hip/hip_bf16.h>
#include <math.h>

// EnhancedTransformerBlock on MI355X — Round 5: deep-pipelined 256-wide MFMA GEMM
// (T2 swizzle + T3/T4 counted-vmcnt double-buffer + T5 setprio), MFMA flash attn
// (round-4, unchanged), fused adaLN.
// GEMM: BM=256, BK=64, 512 thr (8 waves), BN=256 (FFN1) or BN=128 (N<=1024 shapes).
// LDS double-buffered (128/96 KiB dynamic). Staging via global_load_lds with
// pre-swizzled source (slot ^= row&7); fragment ds_read_b128 applies the same XOR
// -> 2-way banks (free). Raw s_barrier + asm waitcnt; vmcnt(8/6) counted, never 0
// in the main loop.

#define HDIM 1024
#define NHEAD 16
#define DHEAD 64
#define NBATCH 8
#define NSEQ 1024
#define NTOK (NBATCH * NSEQ)   // 8192
#define LNEPS 1e-5f
#define LOG2E_8 0.180336880f   // log2(e)/8

using f32x4 = __attribute__((ext_vector_type(4))) float;
using s16x8 = __attribute__((ext_vector_type(8))) short;
using u16x8 = __attribute__((ext_vector_type(8))) unsigned short;

enum { ACT_NONE = 0, ACT_GELU = 1, ACT_RELU = 2, ACT_SIG = 3 };

__device__ inline float bf2f(unsigned short u) {
    union { unsigned u; float f; } t; t.u = ((unsigned)u) << 16; return t.f;
}
__device__ inline unsigned short f2bf(float f) {
    __hip_bfloat16 h = __float2bfloat16(f);
    return *reinterpret_cast<unsigned short*>(&h);
}
__device__ inline float gelu_f(float t) {
    // tanh-form GELU (max abs err ~1e-3; threshold margin is ~6x larger)
    const float u = t * (0.7978845608f + 0.0356774081f * t * t);
    const float e = __expf(2.f * u);
    const float th = 1.f - 2.f / (e + 1.f);
    return 0.5f * t * (1.f + th);
}

#define GLDS16(g, l) __builtin_amdgcn_global_load_lds( \
    (__attribute__((address_space(1))) void*)(g),      \
    (__attribute__((address_space(3))) void*)(l), 16, 0, 0)

// ---------------------------------------------------------------------------
// fp32 -> bf16 cast
// ---------------------------------------------------------------------------
__global__ __launch_bounds__(256)
void cast_bf16_k(const float* __restrict__ in, unsigned short* __restrict__ out, int n4)
{
    for (int i = blockIdx.x * 256 + threadIdx.x; i < n4; i += gridDim.x * 256) {
        float4 v = ((const float4*)in)[i];
        ushort4 o;
        o.x = f2bf(v.x); o.y = f2bf(v.y); o.z = f2bf(v.z); o.w = f2bf(v.w);
        ((ushort4*)out)[i] = o;
    }
}

// ---------------------------------------------------------------------------
// W[K,N] fp32 -> Wt[N,K] bf16
// ---------------------------------------------------------------------------
__global__ __launch_bounds__(256)
void transpose_cast_k(const float* __restrict__ W, unsigned short* __restrict__ Wt,
                      int K, int N)
{
    __shared__ float tile[32][33];
    const int tx = threadIdx.x, ty = threadIdx.y;
    const int k0 = blockIdx.y * 32, n0 = blockIdx.x * 32;
#pragma unroll
    for (int r = 0; r < 32; r += 8)
        tile[ty + r][tx] = W[(size_t)(k0 + ty + r) * N + n0 + tx];
    __syncthreads();
#pragma unroll
    for (int r = 0; r < 32; r += 8)
        Wt[(size_t)(n0 + ty + r) * K + k0 + tx] = f2bf(tile[tx][ty + r]);
}

// ---------------------------------------------------------------------------
// V -> Vt[(b*NHEAD+h)*64+d][s]
// ---------------------------------------------------------------------------
__global__ __launch_bounds__(256)
void transpose_v_k(const unsigned short* __restrict__ vb, unsigned short* __restrict__ vtb)
{
    __shared__ unsigned short t[64][72];
    const int tid = threadIdx.x;
    const int b = blockIdx.z, h = blockIdx.y;
    const int s0 = blockIdx.x * 64;
    {
        const int r = tid >> 3, c = (tid & 7) * 8;
        *(u16x8*)&t[r][c] =
            *(const u16x8*)&vb[((size_t)(b * NSEQ + s0 + r)) * HDIM + h * DHEAD + c];
        *(u16x8*)&t[r + 32][c] =
            *(const u16x8*)&vb[((size_t)(b * NSEQ + s0 + r + 32)) * HDIM + h * DHEAD + c];
    }
    __syncthreads();
    {
        const int d = tid & 63, sc = (tid >> 6) * 16;
        u16x8 o0, o1;
#pragma unroll
        for (int i = 0; i < 8; ++i) o0[i] = t[sc + i][d];
#pragma unroll
        for (int i = 0; i < 8; ++i) o1[i] = t[sc + 8 + i][d];
        unsigned short* dst = &vtb[((size_t)((b * NHEAD + h) * DHEAD + d)) * NSEQ + s0 + sc];
        *(u16x8*)dst = o0;
        *(u16x8*)(dst + 8) = o1;
    }
}

// ---------------------------------------------------------------------------
// Deep-pipelined bf16 MFMA GEMM. C[M,N] = act(A[M,K] @ Bt[N,K]^T + bias (+add)).
// BM=256, BK=64, 512 threads (8 waves). BN=256: 2Mx4N waves, acc 8x4.
// BN=128: 4Mx2N waves, acc 4x4. Double-buffered LDS, counted vmcnt, XOR swizzle.
// ---------------------------------------------------------------------------
template<int BN, int ACT, bool HAS_ADD, bool OUT_BF>
__global__ __launch_bounds__(512, 2)
void gemm8_k(const unsigned short* __restrict__ A, const unsigned short* __restrict__ Bt,
             const float* __restrict__ bias, const float* __restrict__ add,
             void* __restrict__ Cv, int M, int N, int K)
{
    extern __shared__ __align__(16) unsigned short lds[];
    constexpr int BM = 256, BK = 64;
    constexpr int WN = (BN == 256) ? 4 : 2;
    constexpr int WM = 8 / WN;
    constexpr int MREP = BM / (WM * 16);      // 8 or 4
    constexpr int NREP = BN / (WN * 16);      // 4
    constexpr int ASZ = BM * BK;              // 16384 shorts = 32 KiB
    constexpr int BSZ = BN * BK;
    constexpr int AR = 4;
    constexpr int BR = (BN == 256) ? 4 : 2;
    constexpr int NSPLIT = (BN == 256) ? 2 : 1;
    constexpr int NPH = 2 * NSPLIT;
    constexpr int MI_PER = MREP / 2;          // 4 or 2
    constexpr int NJ_PER = NREP / NSPLIT;     // 2 or 4

    const int tid = threadIdx.x;
    const int lane = tid & 63;
    const int w = tid >> 6;
    const int wr = w / WN;
    const int wc = w % WN;
    const int m0 = blockIdx.y * BM;
    const int n0 = blockIdx.x * BN;
    const int fr = lane & 15;
    const int fo = lane >> 4;

    // staging: thread covers 16B slot (tid&7) of row (j*64 + tid>>3); source
    // chunk pre-swizzled so LDS holds (row, slot) = global chunk slot^(row&7)
    const int srow = tid >> 3;
    const int sslot = (tid & 7) ^ (srow & 7);
    const size_t a_base = (size_t)(m0 + srow) * K + sslot * 8;
    const size_t b_base = (size_t)(n0 + srow) * K + sslot * 8;

    f32x4 acc[MREP][NREP] = {};

    auto stage = [&](int t) {
        const int buf = t & 1;
        unsigned short* ad = lds + buf * ASZ + w * 512;
        unsigned short* bd = lds + 2 * ASZ + buf * BSZ + w * 512;
        const unsigned short* as_ = A + a_base + (size_t)t * BK;
        const unsigned short* bs_ = Bt + b_base + (size_t)t * BK;
#pragma unroll
        for (int j = 0; j < AR; ++j)
            GLDS16(as_ + (size_t)j * 64 * K, ad + j * 4096);
#pragma unroll
        for (int j = 0; j < BR; ++j)
            GLDS16(bs_ + (size_t)j * 64 * K, bd + j * 4096);
    };

    const int NT = K / BK;
    stage(0);

    for (int t = 0; t < NT; ++t) {
        if (t + 1 < NT) {
            stage(t + 1);
            if constexpr (BN == 256) asm volatile("s_waitcnt vmcnt(8)" ::: "memory");
            else                     asm volatile("s_waitcnt vmcnt(6)" ::: "memory");
        } else {
            asm volatile("s_waitcnt vmcnt(0)" ::: "memory");
        }
        __builtin_amdgcn_s_barrier();

        const char* Ab = (const char*)(lds + (t & 1) * ASZ);
        const char* Bb = (const char*)(lds + 2 * ASZ + (t & 1) * BSZ);

#pragma unroll
        for (int ph = 0; ph < NPH; ++ph) {
            const int mh = ph / NSPLIT, nh = ph % NSPLIT;
            s16x8 af[MI_PER][2], bfr[NJ_PER][2];
#pragma unroll
            for (int i = 0; i < MI_PER; ++i) {
                const int row = wr * (BM / WM) + (mh * MI_PER + i) * 16 + fr;
                const int sw = (row & 7) << 4;
#pragma unroll
                for (int kk = 0; kk < 2; ++kk)
                    af[i][kk] = *(const s16x8*)(Ab + row * 128 + ((kk * 64 + fo * 16) ^ sw));
            }
#pragma unroll
            for (int j = 0; j < NJ_PER; ++j) {
                const int row = wc * 64 + (nh * NJ_PER + j) * 16 + fr;
                const int sw = (row & 7) << 4;
#pragma unroll
                for (int kk = 0; kk < 2; ++kk)
                    bfr[j][kk] = *(const s16x8*)(Bb + row * 128 + ((kk * 64 + fo * 16) ^ sw));
            }
            __builtin_amdgcn_s_setprio(1);
#pragma unroll
            for (int i = 0; i < MI_PER; ++i)
#pragma unroll
                for (int j = 0; j < NJ_PER; ++j)
#pragma unroll
                    for (int kk = 0; kk < 2; ++kk)
                        acc[mh * MI_PER + i][nh * NJ_PER + j] =
                            __builtin_amdgcn_mfma_f32_16x16x32_bf16(
                                af[i][kk], bfr[j][kk],
                                acc[mh * MI_PER + i][nh * NJ_PER + j], 0, 0, 0);
            __builtin_amdgcn_s_setprio(0);
            asm volatile("s_waitcnt lgkmcnt(0)" ::: "memory");
            __builtin_amdgcn_s_barrier();
        }
    }

    float bv[NREP];
#pragma unroll
    for (int j = 0; j < NREP; ++j)
        bv[j] = bias[n0 + wc * 64 + j * 16 + fr];
#pragma unroll
    for (int i = 0; i < MREP; ++i) {
#pragma unroll
        for (int j = 0; j < NREP; ++j) {
            const int gn = n0 + wc * 64 + j * 16 + fr;
#pragma unroll
            for (int r = 0; r < 4; ++r) {
                const int gm = m0 + wr * (BM / WM) + i * 16 + fo * 4 + r;
                float t = acc[i][j][r] + bv[j];
                if (HAS_ADD) t += add[(size_t)gm * N + gn];
                if (ACT == ACT_GELU)      t = gelu_f(t);
                else if (ACT == ACT_RELU) t = fmaxf(t, 0.f);
                else if (ACT == ACT_SIG)  t = 1.f / (1.f + __expf(-t));
                if (OUT_BF) ((unsigned short*)Cv)[(size_t)gm * N + gn] = f2bf(t);
                else        ((float*)Cv)[(size_t)gm * N + gn] = t;
            }
        }
    }
}

// ---------------------------------------------------------------------------
// MFMA flash attention (round-4, unchanged)
// ---------------------------------------------------------------------------
__global__ __launch_bounds__(256)
void attn_k(const unsigned short* __restrict__ Qb, const unsigned short* __restrict__ Kb,
            const unsigned short* __restrict__ Vtb, unsigned short* __restrict__ Cb)
{
    __shared__ alignas(16) unsigned short Ks[64 * 64];
    __shared__ alignas(16) unsigned short Vs[64 * 64];
    __shared__ alignas(16) unsigned short Ps[4][16 * 72];

    const int tid = threadIdx.x;
    const int lane = tid & 63;
    const int wid = tid >> 6;
    const int b = blockIdx.z, h = blockIdx.y;
    const int q0 = blockIdx.x * 64 + wid * 16;

    const int kcol = lane & 15;
    const int kofs = (lane >> 4) * 8;
    const size_t qoff = ((size_t)(b * NSEQ + q0 + kcol)) * HDIM + h * DHEAD + kofs;
    const s16x8 qf0 = *(const s16x8*)(Qb + qoff);
    const s16x8 qf1 = *(const s16x8*)(Qb + qoff + 32);

    f32x4 accO[4] = {};
    float mrow[4] = {-1e30f, -1e30f, -1e30f, -1e30f};
    float lrow[4] = {0.f, 0.f, 0.f, 0.f};

    const int lr = lane >> 3;
    const int swz8 = (((lane & 7) ^ lr)) * 8;
    const size_t kbase  = ((size_t)(b * NSEQ)) * HDIM + h * DHEAD;
    const size_t vtbase = ((size_t)((b * NHEAD + h) * DHEAD)) * NSEQ;

    unsigned short* const pw = &Ps[wid][0];
    const int prow = (lane >> 4) * 4;

    for (int kt = 0; kt < NSEQ / 64; ++kt) {
        __syncthreads();
#pragma unroll
        for (int j = 0; j < 2; ++j) {
            const int rowb = wid * 16 + j * 8;
            GLDS16(Kb + kbase + (size_t)(kt * 64 + rowb + lr) * HDIM + swz8,
                   Ks + rowb * 64);
            GLDS16(Vtb + vtbase + (size_t)(rowb + lr) * NSEQ + kt * 64 + swz8,
                   Vs + rowb * 64);
        }
        __syncthreads();

        f32x4 sa[4];
#pragma unroll
        for (int jt = 0; jt < 4; ++jt) {
            const int kr = jt * 16 + kcol;
            const unsigned swz = ((unsigned)(kr & 7)) << 4;
            const s16x8 kf0 = *(const s16x8*)((const char*)Ks + kr * 128 + ((kofs * 2) ^ swz));
            const s16x8 kf1 = *(const s16x8*)((const char*)Ks + kr * 128 + ((64 + kofs * 2) ^ swz));
            f32x4 t = {};
            t = __builtin_amdgcn_mfma_f32_16x16x32_bf16(qf0, kf0, t, 0, 0, 0);
            t = __builtin_amdgcn_mfma_f32_16x16x32_bf16(qf1, kf1, t, 0, 0, 0);
            sa[jt] = t * LOG2E_8;
        }

        float p[4][4];
        float corr[4];
#pragma unroll
        for (int r = 0; r < 4; ++r) {
            float mx = fmaxf(fmaxf(sa[0][r], sa[1][r]), fmaxf(sa[2][r], sa[3][r]));
            mx = fmaxf(mx, __shfl_xor(mx, 1));
            mx = fmaxf(mx, __shfl_xor(mx, 2));
            mx = fmaxf(mx, __shfl_xor(mx, 4));
            mx = fmaxf(mx, __shfl_xor(mx, 8));
            const float mn = fmaxf(mrow[r], mx);
            corr[r] = exp2f(mrow[r] - mn);
            mrow[r] = mn;
            float ps = 0.f;
#pragma unroll
            for (int jt = 0; jt < 4; ++jt) {
                p[jt][r] = exp2f(sa[jt][r] - mn);
                ps += p[jt][r];
            }
            ps += __shfl_xor(ps, 1);
            ps += __shfl_xor(ps, 2);
            ps += __shfl_xor(ps, 4);
            ps += __shfl_xor(ps, 8);
            lrow[r] = lrow[r] * corr[r] + ps;
        }

#pragma unroll
        for (int r = 0; r < 4; ++r)
#pragma unroll
            for (int jt = 0; jt < 4; ++jt)
                pw[(prow + r) * 72 + jt * 16 + kcol] = f2bf(p[jt][r]);

#pragma unroll
        for (int dt = 0; dt < 4; ++dt)
#pragma unroll
            for (int r = 0; r < 4; ++r)
                accO[dt][r] *= corr[r];

#pragma unroll
        for (int kc = 0; kc < 2; ++kc) {
            const s16x8 pa = *(const s16x8*)(pw + kcol * 72 + kc * 32 + kofs);
#pragma unroll
            for (int dt = 0; dt < 4; ++dt) {
                const int dr = dt * 16 + kcol;
                const unsigned swz = ((unsigned)(dr & 7)) << 4;
                const s16x8 vf = *(const s16x8*)((const char*)Vs + dr * 128 +
                                                 ((kc * 64 + kofs * 2) ^ swz));
                accO[dt] = __builtin_amdgcn_mfma_f32_16x16x32_bf16(pa, vf, accO[dt], 0, 0, 0);
            }
        }
    }

    const size_t obase = ((size_t)(b * NSEQ + q0 + prow)) * HDIM + h * DHEAD;
#pragma unroll
    for (int r = 0; r < 4; ++r) {
        const float rl = 1.f / lrow[r];
#pragma unroll
        for (int dt = 0; dt < 4; ++dt)
            Cb[obase + (size_t)r * HDIM + dt * 16 + kcol] = f2bf(accO[dt][r] * rl);
    }
}

// ---------------------------------------------------------------------------
// ada-LayerNorm (unchanged)
// ---------------------------------------------------------------------------
template<int MODE, bool WRITE_BF>
__global__ __launch_bounds__(256)
void adaln_k(const float* __restrict__ a, const float* __restrict__ fo,
             const float* __restrict__ g, const float* __restrict__ vol,
             const float* __restrict__ lw, const float* __restrict__ lb,
             const float* __restrict__ gm, const float* __restrict__ bt,
             const float* __restrict__ vsw, const float* __restrict__ vsb,
             float* __restrict__ out, unsigned short* __restrict__ out_bf)
{
    const int tok = blockIdx.x;
    const int tid = threadIdx.x;
    const size_t base = (size_t)tok * HDIM + tid * 4;
    float v[4];
    {
        float4 va = *(const float4*)&a[base];
        if (MODE == 1) {
            float4 vf = *(const float4*)&fo[base];
            float4 vg = *(const float4*)&g[base];
            v[0] = va.x * (2.f - vg.x) + vf.x * vg.x;
            v[1] = va.y * (2.f - vg.y) + vf.y * vg.y;
            v[2] = va.z * (2.f - vg.z) + vf.z * vg.z;
            v[3] = va.w * (2.f - vg.w) + vf.w * vg.w;
        } else {
            v[0] = va.x; v[1] = va.y; v[2] = va.z; v[3] = va.w;
        }
    }
    float sum = v[0] + v[1] + v[2] + v[3];
    float sq  = v[0]*v[0] + v[1]*v[1] + v[2]*v[2] + v[3]*v[3];
#pragma unroll
    for (int off = 32; off > 0; off >>= 1) {
        sum += __shfl_down(sum, off);
        sq  += __shfl_down(sq, off);
    }
    __shared__ float ssum[4], ssq[4];
    const int wid = tid >> 6, lane = tid & 63;
    if (lane == 0) { ssum[wid] = sum; ssq[wid] = sq; }
    __syncthreads();
    const float tsum = ssum[0] + ssum[1] + ssum[2] + ssum[3];
    const float tsq  = ssq[0]  + ssq[1]  + ssq[2]  + ssq[3];
    const float mu   = tsum * (1.f / 1024.f);
    const float var  = tsq * (1.f / 1024.f) - mu * mu;
    const float rstd = rsqrtf(var + LNEPS);
    const float vsv  = 1.f / (1.f + __expf(-(vol[tok] * vsw[0] + vsb[0])));
    const float sca  = (1.f + vsv) * gm[0];
    const float off2 = bt[0];
    const float4 lwv = *(const float4*)&lw[tid * 4];
    const float4 lbv = *(const float4*)&lb[tid * 4];
    float r0 = ((v[0] - mu) * rstd * lwv.x + lbv.x) * sca + off2;
    float r1 = ((v[1] - mu) * rstd * lwv.y + lbv.y) * sca + off2;
    float r2 = ((v[2] - mu) * rstd * lwv.z + lbv.z) * sca + off2;
    float r3 = ((v[3] - mu) * rstd * lwv.w + lbv.w) * sca + off2;
    *(float4*)&out[base] = make_float4(r0, r1, r2, r3);
    if (WRITE_BF) {
        ushort4 ob;
        ob.x = f2bf(r0); ob.y = f2bf(r1); ob.z = f2bf(r2); ob.w = f2bf(r3);
        *(ushort4*)&out_bf[base] = ob;
    }
}

// ---------------------------------------------------------------------------
extern "C" void kernel_launch(void* const* d_in, const int* in_sizes, int n_in,
                              void* d_out, int out_size, void* d_ws, size_t ws_size,
                              hipStream_t stream)
{
    (void)in_sizes; (void)n_in; (void)out_size; (void)ws_size;
    const float* x    = (const float*)d_in[0];
    const float* vol  = (const float*)d_in[1];
    const float* Wq   = (const float*)d_in[2];  const float* bq  = (const float*)d_in[3];
    const float* Wk   = (const float*)d_in[4];  const float* bk  = (const float*)d_in[5];
    const float* Wv   = (const float*)d_in[6];  const float* bv  = (const float*)d_in[7];
    const float* Wo   = (const float*)d_in[8];  const float* bo  = (const float*)d_in[9];
    const float* ln1w = (const float*)d_in[10]; const float* ln1b = (const float*)d_in[11];
    const float* gm1  = (const float*)d_in[12]; const float* be1 = (const float*)d_in[13];
    const float* vs1w = (const float*)d_in[14]; const float* vs1b = (const float*)d_in[15];
    const float* fw1  = (const float*)d_in[16]; const float* fb1 = (const float*)d_in[17];
    const float* fw2  = (const float*)d_in[18]; const float* fb2 = (const float*)d_in[19];
    const float* gw1  = (const float*)d_in[20]; const float* gb1 = (const float*)d_in[21];
    const float* gw2  = (const float*)d_in[22]; const float* gb2 = (const float*)d_in[23];
    const float* ln2w = (const float*)d_in[24]; const float* ln2b = (const float*)d_in[25];
    const float* gm2  = (const float*)d_in[26]; const float* be2 = (const float*)d_in[27];
    const float* vs2w = (const float*)d_in[28]; const float* vs2b = (const float*)d_in[29];

    char* w = (char*)d_ws;
    auto MB = [](size_t v) { return v << 20; };
    unsigned short* wtq  = (unsigned short*)(w + MB(0));
    unsigned short* wtk  = (unsigned short*)(w + MB(2));
    unsigned short* wtv  = (unsigned short*)(w + MB(4));
    unsigned short* wto  = (unsigned short*)(w + MB(6));
    unsigned short* wtf1 = (unsigned short*)(w + MB(8));
    unsigned short* wtf2 = (unsigned short*)(w + MB(16));
    unsigned short* wtg1 = (unsigned short*)(w + MB(24));
    unsigned short* wtg2 = (unsigned short*)(w + MB(25));
    unsigned short* xb  = (unsigned short*)(w + MB(26));
    unsigned short* qb  = (unsigned short*)(w + MB(42));
    unsigned short* kb  = (unsigned short*)(w + MB(58));
    unsigned short* vb  = (unsigned short*)(w + MB(74));
    unsigned short* cxb = (unsigned short*)(w + MB(90));
    float*          ao  = (float*)(w + MB(106));
    unsigned short* vtb = (unsigned short*)(w + MB(106));  // lives only during attn
    float*          x1  = (float*)(w + MB(138));
    unsigned short* x1b = (unsigned short*)(w + MB(170));
    unsigned short* hb  = (unsigned short*)(w + MB(42));
    float*          ffn = (float*)(w + MB(106));
    unsigned short* ghb = (unsigned short*)(w + MB(26));
    float*          gg  = (float*)(w + MB(42));

    dim3 blk(256);
    dim3 tb(32, 8);
    transpose_cast_k<<<dim3(1024/32, 1024/32), tb, 0, stream>>>(Wq, wtq, 1024, 1024);
    transpose_cast_k<<<dim3(1024/32, 1024/32), tb, 0, stream>>>(Wk, wtk, 1024, 1024);
    transpose_cast_k<<<dim3(1024/32, 1024/32), tb, 0, stream>>>(Wv, wtv, 1024, 1024);
    transpose_cast_k<<<dim3(1024/32, 1024/32), tb, 0, stream>>>(Wo, wto, 1024, 1024);
    transpose_cast_k<<<dim3(4096/32, 1024/32), tb, 0, stream>>>(fw1, wtf1, 1024, 4096);
    transpose_cast_k<<<dim3(1024/32, 4096/32), tb, 0, stream>>>(fw2, wtf2, 4096, 1024);
    transpose_cast_k<<<dim3(512/32, 1024/32),  tb, 0, stream>>>(gw1, wtg1, 1024, 512);
    transpose_cast_k<<<dim3(1024/32, 512/32),  tb, 0, stream>>>(gw2, wtg2, 512, 1024);
    cast_bf16_k<<<2048, blk, 0, stream>>>(x, xb, NTOK * HDIM / 4);

    const size_t SH256 = 128 * 1024, SH128 = 96 * 1024;
    gemm8_k<128, ACT_NONE, false, true><<<dim3(8, 32), 512, SH128, stream>>>(
        xb, wtq, bq, nullptr, qb, NTOK, HDIM, HDIM);
    gemm8_k<128, ACT_NONE, false, true><<<dim3(8, 32), 512, SH128, stream>>>(
        xb, wtk, bk, nullptr, kb, NTOK, HDIM, HDIM);
    gemm8_k<128, ACT_NONE, false, true><<<dim3(8, 32), 512, SH128, stream>>>(
        xb, wtv, bv, nullptr, vb, NTOK, HDIM, HDIM);
    transpose_v_k<<<dim3(NSEQ / 64, NHEAD, NBATCH), blk, 0, stream>>>(vb, vtb);
    attn_k<<<dim3(NSEQ / 64, NHEAD, NBATCH), blk, 0, stream>>>(qb, kb, vtb, cxb);
    gemm8_k<128, ACT_NONE, true, false><<<dim3(8, 32), 512, SH128, stream>>>(
        cxb, wto, bo, x, ao, NTOK, HDIM, HDIM);
    adaln_k<0, true><<<dim3(NTOK), blk, 0, stream>>>(
        ao, nullptr, nullptr, vol, ln1w, ln1b, gm1, be1, vs1w, vs1b, x1, x1b);
    gemm8_k<256, ACT_GELU, false, true><<<dim3(16, 32), 512, SH256, stream>>>(
        x1b, wtf1, fb1, nullptr, hb, NTOK, 4096, HDIM);
    gemm8_k<128, ACT_NONE, false, false><<<dim3(8, 32), 512, SH128, stream>>>(
        hb, wtf2, fb2, nullptr, ffn, NTOK, HDIM, 4096);
    gemm8_k<128, ACT_RELU, false, true><<<dim3(4, 32), 512, SH128, stream>>>(
        x1b, wtg1, gb1, nullptr, ghb, NTOK, 512, HDIM);
    gemm8_k<128, ACT_SIG, false, false><<<dim3(8, 32), 512, SH128, stream>>>(
        ghb, wtg2, gb2, nullptr, gg, NTOK, HDIM, 512);
    adaln_k<1, false><<<dim3(NTOK), blk, 0, stream>>>(
        x1, ffn, gg, vol, ln2w, ln2b, gm2, be2, vs2w, vs2b, (float*)d_out, nullptr);
}

// Round 6
// 519.042 us; speedup vs baseline: 8.3944x; 1.0116x over previous
//
#include <hip/hip_runtime.h>
#include <hip/hip_bf16.h>
#include <math.h>

// EnhancedTransformerBlock on MI355X — Round 6:
//  * attn v2: double-buffered K/V (T3 2-phase, counted vmcnt), XCD-clustered
//    blockIdx decode, defer-max rescale (T13, THR=8 in exp2 domain).
//  * fused QKV GEMM (N=3072), BM=128/BN=128 GEMM variant (2 blocks/CU) for
//    N<=1024 shapes, FFN1 stays 256x256.
//  * merged H x H weight transposes into one launch.

#define HDIM 1024
#define NHEAD 16
#define DHEAD 64
#define NBATCH 8
#define NSEQ 1024
#define NTOK (NBATCH * NSEQ)   // 8192
#define QKVSTR 3072            // fused qkv row stride
#define LNEPS 1e-5f
#define LOG2E_8 0.180336880f   // log2(e)/8

using f32x4 = __attribute__((ext_vector_type(4))) float;
using s16x8 = __attribute__((ext_vector_type(8))) short;
using u16x8 = __attribute__((ext_vector_type(8))) unsigned short;

enum { ACT_NONE = 0, ACT_GELU = 1, ACT_RELU = 2, ACT_SIG = 3 };

__device__ inline float bf2f(unsigned short u) {
    union { unsigned u; float f; } t; t.u = ((unsigned)u) << 16; return t.f;
}
__device__ inline unsigned short f2bf(float f) {
    __hip_bfloat16 h = __float2bfloat16(f);
    return *reinterpret_cast<unsigned short*>(&h);
}
__device__ inline float gelu_f(float t) {
    const float u = t * (0.7978845608f + 0.0356774081f * t * t);
    const float e = __expf(2.f * u);
    const float th = 1.f - 2.f / (e + 1.f);
    return 0.5f * t * (1.f + th);
}

#define GLDS16(g, l) __builtin_amdgcn_global_load_lds( \
    (__attribute__((address_space(1))) void*)(g),      \
    (__attribute__((address_space(3))) void*)(l), 16, 0, 0)

// ---------------------------------------------------------------------------
__global__ __launch_bounds__(256)
void cast_bf16_k(const float* __restrict__ in, unsigned short* __restrict__ out, int n4)
{
    for (int i = blockIdx.x * 256 + threadIdx.x; i < n4; i += gridDim.x * 256) {
        float4 v = ((const float4*)in)[i];
        ushort4 o;
        o.x = f2bf(v.x); o.y = f2bf(v.y); o.z = f2bf(v.z); o.w = f2bf(v.w);
        ((ushort4*)out)[i] = o;
    }
}

// ---------------------------------------------------------------------------
__global__ __launch_bounds__(256)
void concat3_k(const float* __restrict__ a, const float* __restrict__ b,
               const float* __restrict__ c, float* __restrict__ o)
{
    int i = blockIdx.x * 256 + threadIdx.x;   // grid 12 -> 3072
    o[i] = i < 1024 ? a[i] : (i < 2048 ? b[i - 1024] : c[i - 2048]);
}

// ---------------------------------------------------------------------------
// W[K,N] fp32 -> Wt[N,K] bf16
// ---------------------------------------------------------------------------
__global__ __launch_bounds__(256)
void transpose_cast_k(const float* __restrict__ W, unsigned short* __restrict__ Wt,
                      int K, int N)
{
    __shared__ float tile[32][33];
    const int tx = threadIdx.x, ty = threadIdx.y;
    const int k0 = blockIdx.y * 32, n0 = blockIdx.x * 32;
#pragma unroll
    for (int r = 0; r < 32; r += 8)
        tile[ty + r][tx] = W[(size_t)(k0 + ty + r) * N + n0 + tx];
    __syncthreads();
#pragma unroll
    for (int r = 0; r < 32; r += 8)
        Wt[(size_t)(n0 + ty + r) * K + k0 + tx] = f2bf(tile[tx][ty + r]);
}

// 4 H x H weights in one launch (z selects)
__global__ __launch_bounds__(256)
void transpose_cast4_k(const float* __restrict__ W0, const float* __restrict__ W1,
                       const float* __restrict__ W2, const float* __restrict__ W3,
                       unsigned short* __restrict__ Wt)
{
    __shared__ float tile[32][33];
    const int z = blockIdx.z;
    const float* W = z == 0 ? W0 : z == 1 ? W1 : z == 2 ? W2 : W3;
    unsigned short* dst = Wt + (size_t)z * HDIM * HDIM;
    const int tx = threadIdx.x, ty = threadIdx.y;
    const int k0 = blockIdx.y * 32, n0 = blockIdx.x * 32;
#pragma unroll
    for (int r = 0; r < 32; r += 8)
        tile[ty + r][tx] = W[(size_t)(k0 + ty + r) * HDIM + n0 + tx];
    __syncthreads();
#pragma unroll
    for (int r = 0; r < 32; r += 8)
        dst[(size_t)(n0 + ty + r) * HDIM + k0 + tx] = f2bf(tile[tx][ty + r]);
}

// ---------------------------------------------------------------------------
// V (strided in fused qkv) -> Vt[(b*NHEAD+h)*64+d][s]
// ---------------------------------------------------------------------------
__global__ __launch_bounds__(256)
void transpose_v_k(const unsigned short* __restrict__ vb, unsigned short* __restrict__ vtb)
{
    __shared__ unsigned short t[64][72];
    const int tid = threadIdx.x;
    const int b = blockIdx.z, h = blockIdx.y;
    const int s0 = blockIdx.x * 64;
    {
        const int r = tid >> 3, c = (tid & 7) * 8;
        *(u16x8*)&t[r][c] =
            *(const u16x8*)&vb[((size_t)(b * NSEQ + s0 + r)) * QKVSTR + h * DHEAD + c];
        *(u16x8*)&t[r + 32][c] =
            *(const u16x8*)&vb[((size_t)(b * NSEQ + s0 + r + 32)) * QKVSTR + h * DHEAD + c];
    }
    __syncthreads();
    {
        const int d = tid & 63, sc = (tid >> 6) * 16;
        u16x8 o0, o1;
#pragma unroll
        for (int i = 0; i < 8; ++i) o0[i] = t[sc + i][d];
#pragma unroll
        for (int i = 0; i < 8; ++i) o1[i] = t[sc + 8 + i][d];
        unsigned short* dst = &vtb[((size_t)((b * NHEAD + h) * DHEAD + d)) * NSEQ + s0 + sc];
        *(u16x8*)dst = o0;
        *(u16x8*)(dst + 8) = o1;
    }
}

// ---------------------------------------------------------------------------
// Deep-pipelined bf16 MFMA GEMM. C[M,N] = act(A[M,K] @ Bt[N,K]^T + bias (+add)).
// BK=64, 512 threads (8 waves), double-buffered LDS, counted vmcnt, XOR swizzle.
// BM=BN=256: 2Mx4N waves; BM=BN=128: 4Mx2N waves (64 KiB LDS -> 2 blocks/CU).
// ---------------------------------------------------------------------------
template<int BM, int BN, int ACT, bool HAS_ADD, bool OUT_BF>
__global__ __launch_bounds__(512, (BM == 128) ? 4 : 2)
void gemm8_k(const unsigned short* __restrict__ A, const unsigned short* __restrict__ Bt,
             const float* __restrict__ bias, const float* __restrict__ add,
             void* __restrict__ Cv, int M, int N, int K)
{
    extern __shared__ __align__(16) unsigned short lds[];
    constexpr int BK = 64;
    constexpr int WN = (BN == 256) ? 4 : 2;
    constexpr int WM = 8 / WN;
    constexpr int MREP = BM / (WM * 16);
    constexpr int NREP = BN / (WN * 16);      // 4
    constexpr int ASZ = BM * BK;
    constexpr int BSZ = BN * BK;
    constexpr int AR = BM / 64;
    constexpr int BR = BN / 64;
    constexpr int VM = AR + BR;
    constexpr int NSPLIT = (BN == 256) ? 2 : 1;
    constexpr int NPH = 2 * NSPLIT;
    constexpr int MI_PER = MREP / 2;
    constexpr int NJ_PER = NREP / NSPLIT;

    const int tid = threadIdx.x;
    const int lane = tid & 63;
    const int w = tid >> 6;
    const int wr = w / WN;
    const int wc = w % WN;
    const int m0 = blockIdx.y * BM;
    const int n0 = blockIdx.x * BN;
    const int fr = lane & 15;
    const int fo = lane >> 4;

    const int srow = tid >> 3;
    const int sslot = (tid & 7) ^ (srow & 7);
    const size_t a_base = (size_t)(m0 + srow) * K + sslot * 8;
    const size_t b_base = (size_t)(n0 + srow) * K + sslot * 8;

    f32x4 acc[MREP][NREP] = {};

    auto stage = [&](int t) {
        const int buf = t & 1;
        unsigned short* ad = lds + buf * ASZ + w * 512;
        unsigned short* bd = lds + 2 * ASZ + buf * BSZ + w * 512;
        const unsigned short* as_ = A + a_base + (size_t)t * BK;
        const unsigned short* bs_ = Bt + b_base + (size_t)t * BK;
#pragma unroll
        for (int j = 0; j < AR; ++j)
            GLDS16(as_ + (size_t)j * 64 * K, ad + j * 4096);
#pragma unroll
        for (int j = 0; j < BR; ++j)
            GLDS16(bs_ + (size_t)j * 64 * K, bd + j * 4096);
    };

    const int NT = K / BK;
    stage(0);

    for (int t = 0; t < NT; ++t) {
        if (t + 1 < NT) {
            stage(t + 1);
            asm volatile("s_waitcnt vmcnt(%0)" :: "i"(VM) : "memory");
        } else {
            asm volatile("s_waitcnt vmcnt(0)" ::: "memory");
        }
        __builtin_amdgcn_s_barrier();

        const char* Ab = (const char*)(lds + (t & 1) * ASZ);
        const char* Bb = (const char*)(lds + 2 * ASZ + (t & 1) * BSZ);

#pragma unroll
        for (int ph = 0; ph < NPH; ++ph) {
            const int mh = ph / NSPLIT, nh = ph % NSPLIT;
            s16x8 af[MI_PER][2], bfr[NJ_PER][2];
#pragma unroll
            for (int i = 0; i < MI_PER; ++i) {
                const int row = wr * (BM / WM) + (mh * MI_PER + i) * 16 + fr;
                const int sw = (row & 7) << 4;
#pragma unroll
                for (int kk = 0; kk < 2; ++kk)
                    af[i][kk] = *(const s16x8*)(Ab + row * 128 + ((kk * 64 + fo * 16) ^ sw));
            }
#pragma unroll
            for (int j = 0; j < NJ_PER; ++j) {
                const int row = wc * 64 + (nh * NJ_PER + j) * 16 + fr;
                const int sw = (row & 7) << 4;
#pragma unroll
                for (int kk = 0; kk < 2; ++kk)
                    bfr[j][kk] = *(const s16x8*)(Bb + row * 128 + ((kk * 64 + fo * 16) ^ sw));
            }
            __builtin_amdgcn_s_setprio(1);
#pragma unroll
            for (int i = 0; i < MI_PER; ++i)
#pragma unroll
                for (int j = 0; j < NJ_PER; ++j)
#pragma unroll
                    for (int kk = 0; kk < 2; ++kk)
                        acc[mh * MI_PER + i][nh * NJ_PER + j] =
                            __builtin_amdgcn_mfma_f32_16x16x32_bf16(
                                af[i][kk], bfr[j][kk],
                                acc[mh * MI_PER + i][nh * NJ_PER + j], 0, 0, 0);
            __builtin_amdgcn_s_setprio(0);
            asm volatile("s_waitcnt lgkmcnt(0)" ::: "memory");
            __builtin_amdgcn_s_barrier();
        }
    }

    float bv[NREP];
#pragma unroll
    for (int j = 0; j < NREP; ++j)
        bv[j] = bias[n0 + wc * 64 + j * 16 + fr];
#pragma unroll
    for (int i = 0; i < MREP; ++i) {
#pragma unroll
        for (int j = 0; j < NREP; ++j) {
            const int gn = n0 + wc * 64 + j * 16 + fr;
#pragma unroll
            for (int r = 0; r < 4; ++r) {
                const int gm = m0 + wr * (BM / WM) + i * 16 + fo * 4 + r;
                float t = acc[i][j][r] + bv[j];
                if (HAS_ADD) t += add[(size_t)gm * N + gn];
                if (ACT == ACT_GELU)      t = gelu_f(t);
                else if (ACT == ACT_RELU) t = fmaxf(t, 0.f);
                else if (ACT == ACT_SIG)  t = 1.f / (1.f + __expf(-t));
                if (OUT_BF) ((unsigned short*)Cv)[(size_t)gm * N + gn] = f2bf(t);
                else        ((float*)Cv)[(size_t)gm * N + gn] = t;
            }
        }
    }
}

// ---------------------------------------------------------------------------
// MFMA flash attention v2. 1D grid 2048, XCD-clustered decode: all 16 q-tiles of
// a (b,h) land on one XCD (L2-resident K/V). Double-buffered K/V staging (T3),
// defer-max rescale (T13). Q/K read strided from fused qkv buffer.
// ---------------------------------------------------------------------------
__global__ __launch_bounds__(256)
void attn_k(const unsigned short* __restrict__ QKVb, const unsigned short* __restrict__ Vtb,
            unsigned short* __restrict__ Cb)
{
    __shared__ alignas(16) unsigned short Ks[2][64 * 64];
    __shared__ alignas(16) unsigned short Vs[2][64 * 64];
    __shared__ alignas(16) unsigned short Ps[4][16 * 72];

    const int tid = threadIdx.x;
    const int lane = tid & 63;
    const int wid = tid >> 6;
    // XCD-clustered decode (2048 = 128 bh * 16 qt; xcd = L%8)
    const int L = blockIdx.x;
    const int xcd = L & 7, slot = L >> 3;
    const int bh = xcd + ((slot >> 4) << 3);
    const int qt = slot & 15;
    const int b = bh >> 4, h = bh & 15;
    const int q0 = qt * 64 + wid * 16;

    const int kcol = lane & 15;
    const int kofs = (lane >> 4) * 8;
    const size_t qoff = ((size_t)(b * NSEQ + q0 + kcol)) * QKVSTR + h * DHEAD + kofs;
    const s16x8 qf0 = *(const s16x8*)(QKVb + qoff);
    const s16x8 qf1 = *(const s16x8*)(QKVb + qoff + 32);

    f32x4 accO[4] = {};
    float mrow[4] = {-1e30f, -1e30f, -1e30f, -1e30f};
    float lrow[4] = {0.f, 0.f, 0.f, 0.f};

    const int lr = lane >> 3;
    const int swz8 = (((lane & 7) ^ lr)) * 8;
    const size_t kbase  = ((size_t)(b * NSEQ)) * QKVSTR + HDIM + h * DHEAD;  // K segment
    const size_t vtbase = ((size_t)(bh * DHEAD)) * NSEQ;

    unsigned short* const pw = &Ps[wid][0];
    const int prow = (lane >> 4) * 4;

    auto stage = [&](int kt, int buf) {
#pragma unroll
        for (int j = 0; j < 2; ++j) {
            const int rowb = wid * 16 + j * 8;
            GLDS16(QKVb + kbase + (size_t)(kt * 64 + rowb + lr) * QKVSTR + swz8,
                   Ks[buf] + rowb * 64);
            GLDS16(Vtb + vtbase + (size_t)(rowb + lr) * NSEQ + kt * 64 + swz8,
                   Vs[buf] + rowb * 64);
        }
    };

    stage(0, 0);
    asm volatile("s_waitcnt vmcnt(0)" ::: "memory");
    __syncthreads();

    for (int kt = 0; kt < NSEQ / 64; ++kt) {
        const int cur = kt & 1;
        if (kt + 1 < NSEQ / 64) stage(kt + 1, cur ^ 1);

        // ---- QK^T
        f32x4 sa[4];
#pragma unroll
        for (int jt = 0; jt < 4; ++jt) {
            const int kr = jt * 16 + kcol;
            const unsigned swz = ((unsigned)(kr & 7)) << 4;
            const s16x8 kf0 = *(const s16x8*)((const char*)Ks[cur] + kr * 128 + ((kofs * 2) ^ swz));
            const s16x8 kf1 = *(const s16x8*)((const char*)Ks[cur] + kr * 128 + ((64 + kofs * 2) ^ swz));
            f32x4 t = {};
            t = __builtin_amdgcn_mfma_f32_16x16x32_bf16(qf0, kf0, t, 0, 0, 0);
            t = __builtin_amdgcn_mfma_f32_16x16x32_bf16(qf1, kf1, t, 0, 0, 0);
            sa[jt] = t * LOG2E_8;
        }

        // ---- online softmax with defer-max (THR=8 in exp2 domain)
        float mx[4];
#pragma unroll
        for (int r = 0; r < 4; ++r) {
            float m = fmaxf(fmaxf(sa[0][r], sa[1][r]), fmaxf(sa[2][r], sa[3][r]));
            m = fmaxf(m, __shfl_xor(m, 1));
            m = fmaxf(m, __shfl_xor(m, 2));
            m = fmaxf(m, __shfl_xor(m, 4));
            m = fmaxf(m, __shfl_xor(m, 8));
            mx[r] = m;
        }
        float dmax = fmaxf(fmaxf(mx[0] - mrow[0], mx[1] - mrow[1]),
                           fmaxf(mx[2] - mrow[2], mx[3] - mrow[3]));
        if (!__all(dmax <= 8.f)) {
#pragma unroll
            for (int r = 0; r < 4; ++r) {
                const float mn = fmaxf(mrow[r], mx[r]);
                const float corr = exp2f(mrow[r] - mn);
                mrow[r] = mn;
                lrow[r] *= corr;
#pragma unroll
                for (int dt = 0; dt < 4; ++dt) accO[dt][r] *= corr;
            }
        }
#pragma unroll
        for (int r = 0; r < 4; ++r) {
            float ps = 0.f;
#pragma unroll
            for (int jt = 0; jt < 4; ++jt) {
                const float p = exp2f(sa[jt][r] - mrow[r]);
                pw[(prow + r) * 72 + jt * 16 + kcol] = f2bf(p);
                ps += p;
            }
            ps += __shfl_xor(ps, 1);
            ps += __shfl_xor(ps, 2);
            ps += __shfl_xor(ps, 4);
            ps += __shfl_xor(ps, 8);
            lrow[r] += ps;
        }

        // ---- PV
#pragma unroll
        for (int kc = 0; kc < 2; ++kc) {
            const s16x8 pa = *(const s16x8*)(pw + kcol * 72 + kc * 32 + kofs);
#pragma unroll
            for (int dt = 0; dt < 4; ++dt) {
                const int dr = dt * 16 + kcol;
                const unsigned swz = ((unsigned)(dr & 7)) << 4;
                const s16x8 vf = *(const s16x8*)((const char*)Vs[cur] + dr * 128 +
                                                 ((kc * 64 + kofs * 2) ^ swz));
                accO[dt] = __builtin_amdgcn_mfma_f32_16x16x32_bf16(pa, vf, accO[dt], 0, 0, 0);
            }
        }

        if (kt + 1 < NSEQ / 64) asm volatile("s_waitcnt vmcnt(0)" ::: "memory");
        __builtin_amdgcn_s_barrier();
    }

    const size_t obase = ((size_t)(b * NSEQ + q0 + prow)) * HDIM + h * DHEAD;
#pragma unroll
    for (int r = 0; r < 4; ++r) {
        const float rl = 1.f / lrow[r];
#pragma unroll
        for (int dt = 0; dt < 4; ++dt)
            Cb[obase + (size_t)r * HDIM + dt * 16 + kcol] = f2bf(accO[dt][r] * rl);
    }
}

// ---------------------------------------------------------------------------
// ada-LayerNorm (unchanged)
// ---------------------------------------------------------------------------
template<int MODE, bool WRITE_BF>
__global__ __launch_bounds__(256)
void adaln_k(const float* __restrict__ a, const float* __restrict__ fo,
             const float* __restrict__ g, const float* __restrict__ vol,
             const float* __restrict__ lw, const float* __restrict__ lb,
             const float* __restrict__ gm, const float* __restrict__ bt,
             const float* __restrict__ vsw, const float* __restrict__ vsb,
             float* __restrict__ out, unsigned short* __restrict__ out_bf)
{
    const int tok = blockIdx.x;
    const int tid = threadIdx.x;
    const size_t base = (size_t)tok * HDIM + tid * 4;
    float v[4];
    {
        float4 va = *(const float4*)&a[base];
        if (MODE == 1) {
            float4 vf = *(const float4*)&fo[base];
            float4 vg = *(const float4*)&g[base];
            v[0] = va.x * (2.f - vg.x) + vf.x * vg.x;
            v[1] = va.y * (2.f - vg.y) + vf.y * vg.y;
            v[2] = va.z * (2.f - vg.z) + vf.z * vg.z;
            v[3] = va.w * (2.f - vg.w) + vf.w * vg.w;
        } else {
            v[0] = va.x; v[1] = va.y; v[2] = va.z; v[3] = va.w;
        }
    }
    float sum = v[0] + v[1] + v[2] + v[3];
    float sq  = v[0]*v[0] + v[1]*v[1] + v[2]*v[2] + v[3]*v[3];
#pragma unroll
    for (int off = 32; off > 0; off >>= 1) {
        sum += __shfl_down(sum, off);
        sq  += __shfl_down(sq, off);
    }
    __shared__ float ssum[4], ssq[4];
    const int wid = tid >> 6, lane = tid & 63;
    if (lane == 0) { ssum[wid] = sum; ssq[wid] = sq; }
    __syncthreads();
    const float tsum = ssum[0] + ssum[1] + ssum[2] + ssum[3];
    const float tsq  = ssq[0]  + ssq[1]  + ssq[2]  + ssq[3];
    const float mu   = tsum * (1.f / 1024.f);
    const float var  = tsq * (1.f / 1024.f) - mu * mu;
    const float rstd = rsqrtf(var + LNEPS);
    const float vsv  = 1.f / (1.f + __expf(-(vol[tok] * vsw[0] + vsb[0])));
    const float sca  = (1.f + vsv) * gm[0];
    const float off2 = bt[0];
    const float4 lwv = *(const float4*)&lw[tid * 4];
    const float4 lbv = *(const float4*)&lb[tid * 4];
    float r0 = ((v[0] - mu) * rstd * lwv.x + lbv.x) * sca + off2;
    float r1 = ((v[1] - mu) * rstd * lwv.y + lbv.y) * sca + off2;
    float r2 = ((v[2] - mu) * rstd * lwv.z + lbv.z) * sca + off2;
    float r3 = ((v[3] - mu) * rstd * lwv.w + lbv.w) * sca + off2;
    *(float4*)&out[base] = make_float4(r0, r1, r2, r3);
    if (WRITE_BF) {
        ushort4 ob;
        ob.x = f2bf(r0); ob.y = f2bf(r1); ob.z = f2bf(r2); ob.w = f2bf(r3);
        *(ushort4*)&out_bf[base] = ob;
    }
}

// ---------------------------------------------------------------------------
extern "C" void kernel_launch(void* const* d_in, const int* in_sizes, int n_in,
                              void* d_out, int out_size, void* d_ws, size_t ws_size,
                              hipStream_t stream)
{
    (void)in_sizes; (void)n_in; (void)out_size; (void)ws_size;
    const float* x    = (const float*)d_in[0];
    const float* vol  = (const float*)d_in[1];
    const float* Wq   = (const float*)d_in[2];  const float* bq  = (const float*)d_in[3];
    const float* Wk   = (const float*)d_in[4];  const float* bk  = (const float*)d_in[5];
    const float* Wv   = (const float*)d_in[6];  const float* bv  = (const float*)d_in[7];
    const float* Wo   = (const float*)d_in[8];  const float* bo  = (const float*)d_in[9];
    const float* ln1w = (const float*)d_in[10]; const float* ln1b = (const float*)d_in[11];
    const float* gm1  = (const float*)d_in[12]; const float* be1 = (const float*)d_in[13];
    const float* vs1w = (const float*)d_in[14]; const float* vs1b = (const float*)d_in[15];
    const float* fw1  = (const float*)d_in[16]; const float* fb1 = (const float*)d_in[17];
    const float* fw2  = (const float*)d_in[18]; const float* fb2 = (const float*)d_in[19];
    const float* gw1  = (const float*)d_in[20]; const float* gb1 = (const float*)d_in[21];
    const float* gw2  = (const float*)d_in[22]; const float* gb2 = (const float*)d_in[23];
    const float* ln2w = (const float*)d_in[24]; const float* ln2b = (const float*)d_in[25];
    const float* gm2  = (const float*)d_in[26]; const float* be2 = (const float*)d_in[27];
    const float* vs2w = (const float*)d_in[28]; const float* vs2b = (const float*)d_in[29];

    char* w = (char*)d_ws;
    auto MB = [](size_t v) { return v << 20; };
    // weights (live whole call): 0-26 MiB; wtq/wtk/wtv contiguous = fused [3072][1024]
    unsigned short* wtqkv = (unsigned short*)(w + MB(0));   // 0-6
    unsigned short* wto   = (unsigned short*)(w + MB(6));
    unsigned short* wtf1  = (unsigned short*)(w + MB(8));
    unsigned short* wtf2  = (unsigned short*)(w + MB(16));
    unsigned short* wtg1  = (unsigned short*)(w + MB(24));
    unsigned short* wtg2  = (unsigned short*)(w + MB(25));
    // phase-packed activations:
    unsigned short* xb   = (unsigned short*)(w + MB(26));   // 26-42
    unsigned short* qkvb = (unsigned short*)(w + MB(42));   // 42-90 [8192][3072]
    unsigned short* vtb  = (unsigned short*)(w + MB(90));   // 90-106
    unsigned short* cxb  = (unsigned short*)(w + MB(106));  // 106-122
    float*          ao   = (float*)(w + MB(122));           // 122-154
    float*          x1   = (float*)(w + MB(42));            // 42-74 (qkv dead)
    unsigned short* x1b  = (unsigned short*)(w + MB(74));   // 74-90
    unsigned short* hb   = (unsigned short*)(w + MB(90));   // 90-154 (vtb/cxb/ao dead)
    float*          ffn  = (float*)(w + MB(154));           // 154-186
    unsigned short* ghb  = (unsigned short*)(w + MB(26));   // 26-34 (xb dead)
    float*          gg   = (float*)(w + MB(90));            // 90-122 (hb dead after FFN2)
    float*          bqkv = (float*)(w + MB(186));           // 12 KB

    dim3 blk(256);
    dim3 tb(32, 8);
    transpose_cast4_k<<<dim3(32, 32, 4), tb, 0, stream>>>(Wq, Wk, Wv, Wo, wtqkv);
    transpose_cast_k<<<dim3(4096/32, 1024/32), tb, 0, stream>>>(fw1, wtf1, 1024, 4096);
    transpose_cast_k<<<dim3(1024/32, 4096/32), tb, 0, stream>>>(fw2, wtf2, 4096, 1024);
    transpose_cast_k<<<dim3(512/32, 1024/32),  tb, 0, stream>>>(gw1, wtg1, 1024, 512);
    transpose_cast_k<<<dim3(1024/32, 512/32),  tb, 0, stream>>>(gw2, wtg2, 512, 1024);
    cast_bf16_k<<<2048, blk, 0, stream>>>(x, xb, NTOK * HDIM / 4);
    concat3_k<<<12, blk, 0, stream>>>(bq, bk, bv, bqkv);

    const size_t SH128 = (128 + 128) * 256;   // 64 KiB
    const size_t SH256 = (256 + 256) * 256;   // 128 KiB
    // fused QKV: [8192][1024] @ [3072][1024]^T -> [8192][3072]
    gemm8_k<128, 128, ACT_NONE, false, true><<<dim3(24, 64), 512, SH128, stream>>>(
        xb, wtqkv, bqkv, nullptr, qkvb, NTOK, QKVSTR, HDIM);
    transpose_v_k<<<dim3(NSEQ / 64, NHEAD, NBATCH), blk, 0, stream>>>(qkvb + 2048, vtb);
    attn_k<<<dim3(2048), blk, 0, stream>>>(qkvb, vtb, cxb);
    gemm8_k<128, 128, ACT_NONE, true, false><<<dim3(8, 64), 512, SH128, stream>>>(
        cxb, wto, bo, x, ao, NTOK, HDIM, HDIM);
    adaln_k<0, true><<<dim3(NTOK), blk, 0, stream>>>(
        ao, nullptr, nullptr, vol, ln1w, ln1b, gm1, be1, vs1w, vs1b, x1, x1b);
    gemm8_k<256, 256, ACT_GELU, false, true><<<dim3(16, 32), 512, SH256, stream>>>(
        x1b, wtf1, fb1, nullptr, hb, NTOK, 4096, HDIM);
    gemm8_k<128, 128, ACT_NONE, false, false><<<dim3(8, 64), 512, SH128, stream>>>(
        hb, wtf2, fb2, nullptr, ffn, NTOK, HDIM, 4096);
    gemm8_k<128, 128, ACT_RELU, false, true><<<dim3(4, 64), 512, SH128, stream>>>(
        x1b, wtg1, gb1, nullptr, ghb, NTOK, 512, HDIM);
    gemm8_k<128, 128, ACT_SIG, false, false><<<dim3(8, 64), 512, SH128, stream>>>(
        ghb, wtg2, gb2, nullptr, gg, NTOK, HDIM, 512);
    adaln_k<1, false><<<dim3(NTOK), blk, 0, stream>>>(
        x1, ffn, gg, vol, ln2w, ln2b, gm2, be2, vs2w, vs2b, (float*)d_out, nullptr);
}

// Round 7
// 503.983 us; speedup vs baseline: 8.6452x; 1.0299x over previous
//
#include <hip/hip_runtime.h>
#include <hip/hip_bf16.h>
#include <math.h>

// EnhancedTransformerBlock on MI355X — Round 7: GEMM inner-loop rework.
//  * snake-ordered quadrant phases: each phase reloads only the changed operand
//    (LDS reads 48->32 per K-tile for 256^2, 24->16 for 128^2 = minimal).
//  * minimal sync: 2 barriers per K-tile (no per-phase lgkmcnt(0) lockstep);
//    lgkmcnt(0)+sched_barrier(0) guard before the closing barrier (rule #18).
//  * attn v2 (dbuf K/V, XCD-clustered, defer-max) unchanged from round 6.

#define HDIM 1024
#define NHEAD 16
#define DHEAD 64
#define NBATCH 8
#define NSEQ 1024
#define NTOK (NBATCH * NSEQ)   // 8192
#define QKVSTR 3072            // fused qkv row stride
#define LNEPS 1e-5f
#define LOG2E_8 0.180336880f   // log2(e)/8

using f32x4 = __attribute__((ext_vector_type(4))) float;
using s16x8 = __attribute__((ext_vector_type(8))) short;
using u16x8 = __attribute__((ext_vector_type(8))) unsigned short;

enum { ACT_NONE = 0, ACT_GELU = 1, ACT_RELU = 2, ACT_SIG = 3 };

__device__ inline float bf2f(unsigned short u) {
    union { unsigned u; float f; } t; t.u = ((unsigned)u) << 16; return t.f;
}
__device__ inline unsigned short f2bf(float f) {
    __hip_bfloat16 h = __float2bfloat16(f);
    return *reinterpret_cast<unsigned short*>(&h);
}
__device__ inline float gelu_f(float t) {
    const float u = t * (0.7978845608f + 0.0356774081f * t * t);
    const float e = __expf(2.f * u);
    const float th = 1.f - 2.f / (e + 1.f);
    return 0.5f * t * (1.f + th);
}

#define GLDS16(g, l) __builtin_amdgcn_global_load_lds( \
    (__attribute__((address_space(1))) void*)(g),      \
    (__attribute__((address_space(3))) void*)(l), 16, 0, 0)

// ---------------------------------------------------------------------------
__global__ __launch_bounds__(256)
void cast_bf16_k(const float* __restrict__ in, unsigned short* __restrict__ out, int n4)
{
    for (int i = blockIdx.x * 256 + threadIdx.x; i < n4; i += gridDim.x * 256) {
        float4 v = ((const float4*)in)[i];
        ushort4 o;
        o.x = f2bf(v.x); o.y = f2bf(v.y); o.z = f2bf(v.z); o.w = f2bf(v.w);
        ((ushort4*)out)[i] = o;
    }
}

// ---------------------------------------------------------------------------
__global__ __launch_bounds__(256)
void concat3_k(const float* __restrict__ a, const float* __restrict__ b,
               const float* __restrict__ c, float* __restrict__ o)
{
    int i = blockIdx.x * 256 + threadIdx.x;   // grid 12 -> 3072
    o[i] = i < 1024 ? a[i] : (i < 2048 ? b[i - 1024] : c[i - 2048]);
}

// ---------------------------------------------------------------------------
// W[K,N] fp32 -> Wt[N,K] bf16
// ---------------------------------------------------------------------------
__global__ __launch_bounds__(256)
void transpose_cast_k(const float* __restrict__ W, unsigned short* __restrict__ Wt,
                      int K, int N)
{
    __shared__ float tile[32][33];
    const int tx = threadIdx.x, ty = threadIdx.y;
    const int k0 = blockIdx.y * 32, n0 = blockIdx.x * 32;
#pragma unroll
    for (int r = 0; r < 32; r += 8)
        tile[ty + r][tx] = W[(size_t)(k0 + ty + r) * N + n0 + tx];
    __syncthreads();
#pragma unroll
    for (int r = 0; r < 32; r += 8)
        Wt[(size_t)(n0 + ty + r) * K + k0 + tx] = f2bf(tile[tx][ty + r]);
}

// 4 H x H weights in one launch (z selects)
__global__ __launch_bounds__(256)
void transpose_cast4_k(const float* __restrict__ W0, const float* __restrict__ W1,
                       const float* __restrict__ W2, const float* __restrict__ W3,
                       unsigned short* __restrict__ Wt)
{
    __shared__ float tile[32][33];
    const int z = blockIdx.z;
    const float* W = z == 0 ? W0 : z == 1 ? W1 : z == 2 ? W2 : W3;
    unsigned short* dst = Wt + (size_t)z * HDIM * HDIM;
    const int tx = threadIdx.x, ty = threadIdx.y;
    const int k0 = blockIdx.y * 32, n0 = blockIdx.x * 32;
#pragma unroll
    for (int r = 0; r < 32; r += 8)
        tile[ty + r][tx] = W[(size_t)(k0 + ty + r) * HDIM + n0 + tx];
    __syncthreads();
#pragma unroll
    for (int r = 0; r < 32; r += 8)
        dst[(size_t)(n0 + ty + r) * HDIM + k0 + tx] = f2bf(tile[tx][ty + r]);
}

// ---------------------------------------------------------------------------
// V (strided in fused qkv) -> Vt[(b*NHEAD+h)*64+d][s]
// ---------------------------------------------------------------------------
__global__ __launch_bounds__(256)
void transpose_v_k(const unsigned short* __restrict__ vb, unsigned short* __restrict__ vtb)
{
    __shared__ unsigned short t[64][72];
    const int tid = threadIdx.x;
    const int b = blockIdx.z, h = blockIdx.y;
    const int s0 = blockIdx.x * 64;
    {
        const int r = tid >> 3, c = (tid & 7) * 8;
        *(u16x8*)&t[r][c] =
            *(const u16x8*)&vb[((size_t)(b * NSEQ + s0 + r)) * QKVSTR + h * DHEAD + c];
        *(u16x8*)&t[r + 32][c] =
            *(const u16x8*)&vb[((size_t)(b * NSEQ + s0 + r + 32)) * QKVSTR + h * DHEAD + c];
    }
    __syncthreads();
    {
        const int d = tid & 63, sc = (tid >> 6) * 16;
        u16x8 o0, o1;
#pragma unroll
        for (int i = 0; i < 8; ++i) o0[i] = t[sc + i][d];
#pragma unroll
        for (int i = 0; i < 8; ++i) o1[i] = t[sc + 8 + i][d];
        unsigned short* dst = &vtb[((size_t)((b * NHEAD + h) * DHEAD + d)) * NSEQ + s0 + sc];
        *(u16x8*)dst = o0;
        *(u16x8*)(dst + 8) = o1;
    }
}

// ---------------------------------------------------------------------------
// Deep-pipelined bf16 MFMA GEMM. C[M,N] = act(A[M,K] @ Bt[N,K]^T + bias (+add)).
// BK=64, 512 threads (8 waves), double-buffered LDS, counted vmcnt, XOR swizzle.
// Snake-ordered phases (min LDS reads), 2 barriers per K-tile.
// BM=BN=256: 2Mx4N waves; BM=BN=128: 4Mx2N waves (64 KiB LDS -> 2 blocks/CU).
// ---------------------------------------------------------------------------
template<int BM, int BN, int ACT, bool HAS_ADD, bool OUT_BF>
__global__ __launch_bounds__(512, (BM == 128) ? 4 : 2)
void gemm8_k(const unsigned short* __restrict__ A, const unsigned short* __restrict__ Bt,
             const float* __restrict__ bias, const float* __restrict__ add,
             void* __restrict__ Cv, int M, int N, int K)
{
    extern __shared__ __align__(16) unsigned short lds[];
    constexpr int BK = 64;
    constexpr int WN = (BN == 256) ? 4 : 2;
    constexpr int WM = 8 / WN;
    constexpr int MREP = BM / (WM * 16);      // 8 or 4
    constexpr int NREP = BN / (WN * 16);      // 4
    constexpr int ASZ = BM * BK;
    constexpr int BSZ = BN * BK;
    constexpr int AR = BM / 64;
    constexpr int BR = BN / 64;
    constexpr int VM = AR + BR;
    constexpr int NPH = (BN == 256) ? 4 : 2;
    constexpr int MI_PER = MREP / 2;          // 4 or 2
    constexpr int NJ_PER = (BN == 256) ? 2 : 4;

    const int tid = threadIdx.x;
    const int lane = tid & 63;
    const int w = tid >> 6;
    const int wr = w / WN;
    const int wc = w % WN;
    const int m0 = blockIdx.y * BM;
    const int n0 = blockIdx.x * BN;
    const int fr = lane & 15;
    const int fo = lane >> 4;

    const int srow = tid >> 3;
    const int sslot = (tid & 7) ^ (srow & 7);
    const size_t a_base = (size_t)(m0 + srow) * K + sslot * 8;
    const size_t b_base = (size_t)(n0 + srow) * K + sslot * 8;

    f32x4 acc[MREP][NREP] = {};

    auto stage = [&](int t) {
        const int buf = t & 1;
        unsigned short* ad = lds + buf * ASZ + w * 512;
        unsigned short* bd = lds + 2 * ASZ + buf * BSZ + w * 512;
        const unsigned short* as_ = A + a_base + (size_t)t * BK;
        const unsigned short* bs_ = Bt + b_base + (size_t)t * BK;
#pragma unroll
        for (int j = 0; j < AR; ++j)
            GLDS16(as_ + (size_t)j * 64 * K, ad + j * 4096);
#pragma unroll
        for (int j = 0; j < BR; ++j)
            GLDS16(bs_ + (size_t)j * 64 * K, bd + j * 4096);
    };

    const int NT = K / BK;
    stage(0);

    for (int t = 0; t < NT; ++t) {
        if (t + 1 < NT) {
            stage(t + 1);
            asm volatile("s_waitcnt vmcnt(%0)" :: "i"(VM) : "memory");
        } else {
            asm volatile("s_waitcnt vmcnt(0)" ::: "memory");
        }
        __builtin_amdgcn_s_barrier();

        const char* Ab = (const char*)(lds + (t & 1) * ASZ);
        const char* Bb = (const char*)(lds + 2 * ASZ + (t & 1) * BSZ);

        // snake phases: 256^2: (mh,nh) = (0,0)->(1,0)->(1,1)->(0,1);
        // 128^2: (0,0)->(1,0). Reload only the operand that changed.
        s16x8 af[MI_PER][2], bfr[NJ_PER][2];
#pragma unroll
        for (int ph = 0; ph < NPH; ++ph) {
            const int mh = (BN == 256) ? ((ph == 1 || ph == 2) ? 1 : 0) : ph;
            const int nh = (BN == 256) ? (ph >> 1) : 0;
            const bool la = (BN != 256) || (ph != 2);
            const bool lb = (BN == 256) ? ((ph & 1) == 0) : (ph == 0);
            if (la) {
#pragma unroll
                for (int i = 0; i < MI_PER; ++i) {
                    const int row = wr * (BM / WM) + (mh * MI_PER + i) * 16 + fr;
                    const int sw = (row & 7) << 4;
#pragma unroll
                    for (int kk = 0; kk < 2; ++kk)
                        af[i][kk] = *(const s16x8*)(Ab + row * 128 + ((kk * 64 + fo * 16) ^ sw));
                }
            }
            if (lb) {
#pragma unroll
                for (int j = 0; j < NJ_PER; ++j) {
                    const int row = wc * 64 + (nh * NJ_PER + j) * 16 + fr;
                    const int sw = (row & 7) << 4;
#pragma unroll
                    for (int kk = 0; kk < 2; ++kk)
                        bfr[j][kk] = *(const s16x8*)(Bb + row * 128 + ((kk * 64 + fo * 16) ^ sw));
                }
            }
            __builtin_amdgcn_s_setprio(1);
#pragma unroll
            for (int i = 0; i < MI_PER; ++i)
#pragma unroll
                for (int j = 0; j < NJ_PER; ++j)
#pragma unroll
                    for (int kk = 0; kk < 2; ++kk)
                        acc[mh * MI_PER + i][nh * NJ_PER + j] =
                            __builtin_amdgcn_mfma_f32_16x16x32_bf16(
                                af[i][kk], bfr[j][kk],
                                acc[mh * MI_PER + i][nh * NJ_PER + j], 0, 0, 0);
            __builtin_amdgcn_s_setprio(0);
        }
        asm volatile("s_waitcnt lgkmcnt(0)" ::: "memory");
        __builtin_amdgcn_sched_barrier(0);   // keep MFMAs/reads from crossing (rule #18)
        __builtin_amdgcn_s_barrier();
    }

    float bv[NREP];
#pragma unroll
    for (int j = 0; j < NREP; ++j)
        bv[j] = bias[n0 + wc * 64 + j * 16 + fr];
#pragma unroll
    for (int i = 0; i < MREP; ++i) {
#pragma unroll
        for (int j = 0; j < NREP; ++j) {
            const int gn = n0 + wc * 64 + j * 16 + fr;
#pragma unroll
            for (int r = 0; r < 4; ++r) {
                const int gm = m0 + wr * (BM / WM) + i * 16 + fo * 4 + r;
                float t = acc[i][j][r] + bv[j];
                if (HAS_ADD) t += add[(size_t)gm * N + gn];
                if (ACT == ACT_GELU)      t = gelu_f(t);
                else if (ACT == ACT_RELU) t = fmaxf(t, 0.f);
                else if (ACT == ACT_SIG)  t = 1.f / (1.f + __expf(-t));
                if (OUT_BF) ((unsigned short*)Cv)[(size_t)gm * N + gn] = f2bf(t);
                else        ((float*)Cv)[(size_t)gm * N + gn] = t;
            }
        }
    }
}

// ---------------------------------------------------------------------------
// MFMA flash attention v2 (round-6, unchanged).
// ---------------------------------------------------------------------------
__global__ __launch_bounds__(256)
void attn_k(const unsigned short* __restrict__ QKVb, const unsigned short* __restrict__ Vtb,
            unsigned short* __restrict__ Cb)
{
    __shared__ alignas(16) unsigned short Ks[2][64 * 64];
    __shared__ alignas(16) unsigned short Vs[2][64 * 64];
    __shared__ alignas(16) unsigned short Ps[4][16 * 72];

    const int tid = threadIdx.x;
    const int lane = tid & 63;
    const int wid = tid >> 6;
    const int L = blockIdx.x;
    const int xcd = L & 7, slot = L >> 3;
    const int bh = xcd + ((slot >> 4) << 3);
    const int qt = slot & 15;
    const int b = bh >> 4, h = bh & 15;
    const int q0 = qt * 64 + wid * 16;

    const int kcol = lane & 15;
    const int kofs = (lane >> 4) * 8;
    const size_t qoff = ((size_t)(b * NSEQ + q0 + kcol)) * QKVSTR + h * DHEAD + kofs;
    const s16x8 qf0 = *(const s16x8*)(QKVb + qoff);
    const s16x8 qf1 = *(const s16x8*)(QKVb + qoff + 32);

    f32x4 accO[4] = {};
    float mrow[4] = {-1e30f, -1e30f, -1e30f, -1e30f};
    float lrow[4] = {0.f, 0.f, 0.f, 0.f};

    const int lr = lane >> 3;
    const int swz8 = (((lane & 7) ^ lr)) * 8;
    const size_t kbase  = ((size_t)(b * NSEQ)) * QKVSTR + HDIM + h * DHEAD;
    const size_t vtbase = ((size_t)(bh * DHEAD)) * NSEQ;

    unsigned short* const pw = &Ps[wid][0];
    const int prow = (lane >> 4) * 4;

    auto stage = [&](int kt, int buf) {
#pragma unroll
        for (int j = 0; j < 2; ++j) {
            const int rowb = wid * 16 + j * 8;
            GLDS16(QKVb + kbase + (size_t)(kt * 64 + rowb + lr) * QKVSTR + swz8,
                   Ks[buf] + rowb * 64);
            GLDS16(Vtb + vtbase + (size_t)(rowb + lr) * NSEQ + kt * 64 + swz8,
                   Vs[buf] + rowb * 64);
        }
    };

    stage(0, 0);
    asm volatile("s_waitcnt vmcnt(0)" ::: "memory");
    __syncthreads();

    for (int kt = 0; kt < NSEQ / 64; ++kt) {
        const int cur = kt & 1;
        if (kt + 1 < NSEQ / 64) stage(kt + 1, cur ^ 1);

        f32x4 sa[4];
#pragma unroll
        for (int jt = 0; jt < 4; ++jt) {
            const int kr = jt * 16 + kcol;
            const unsigned swz = ((unsigned)(kr & 7)) << 4;
            const s16x8 kf0 = *(const s16x8*)((const char*)Ks[cur] + kr * 128 + ((kofs * 2) ^ swz));
            const s16x8 kf1 = *(const s16x8*)((const char*)Ks[cur] + kr * 128 + ((64 + kofs * 2) ^ swz));
            f32x4 t = {};
            t = __builtin_amdgcn_mfma_f32_16x16x32_bf16(qf0, kf0, t, 0, 0, 0);
            t = __builtin_amdgcn_mfma_f32_16x16x32_bf16(qf1, kf1, t, 0, 0, 0);
            sa[jt] = t * LOG2E_8;
        }

        float mx[4];
#pragma unroll
        for (int r = 0; r < 4; ++r) {
            float m = fmaxf(fmaxf(sa[0][r], sa[1][r]), fmaxf(sa[2][r], sa[3][r]));
            m = fmaxf(m, __shfl_xor(m, 1));
            m = fmaxf(m, __shfl_xor(m, 2));
            m = fmaxf(m, __shfl_xor(m, 4));
            m = fmaxf(m, __shfl_xor(m, 8));
            mx[r] = m;
        }
        float dmax = fmaxf(fmaxf(mx[0] - mrow[0], mx[1] - mrow[1]),
                           fmaxf(mx[2] - mrow[2], mx[3] - mrow[3]));
        if (!__all(dmax <= 8.f)) {
#pragma unroll
            for (int r = 0; r < 4; ++r) {
                const float mn = fmaxf(mrow[r], mx[r]);
                const float corr = exp2f(mrow[r] - mn);
                mrow[r] = mn;
                lrow[r] *= corr;
#pragma unroll
                for (int dt = 0; dt < 4; ++dt) accO[dt][r] *= corr;
            }
        }
#pragma unroll
        for (int r = 0; r < 4; ++r) {
            float ps = 0.f;
#pragma unroll
            for (int jt = 0; jt < 4; ++jt) {
                const float p = exp2f(sa[jt][r] - mrow[r]);
                pw[(prow + r) * 72 + jt * 16 + kcol] = f2bf(p);
                ps += p;
            }
            ps += __shfl_xor(ps, 1);
            ps += __shfl_xor(ps, 2);
            ps += __shfl_xor(ps, 4);
            ps += __shfl_xor(ps, 8);
            lrow[r] += ps;
        }

#pragma unroll
        for (int kc = 0; kc < 2; ++kc) {
            const s16x8 pa = *(const s16x8*)(pw + kcol * 72 + kc * 32 + kofs);
#pragma unroll
            for (int dt = 0; dt < 4; ++dt) {
                const int dr = dt * 16 + kcol;
                const unsigned swz = ((unsigned)(dr & 7)) << 4;
                const s16x8 vf = *(const s16x8*)((const char*)Vs[cur] + dr * 128 +
                                                 ((kc * 64 + kofs * 2) ^ swz));
                accO[dt] = __builtin_amdgcn_mfma_f32_16x16x32_bf16(pa, vf, accO[dt], 0, 0, 0);
            }
        }

        if (kt + 1 < NSEQ / 64) asm volatile("s_waitcnt vmcnt(0)" ::: "memory");
        __builtin_amdgcn_s_barrier();
    }

    const size_t obase = ((size_t)(b * NSEQ + q0 + prow)) * HDIM + h * DHEAD;
#pragma unroll
    for (int r = 0; r < 4; ++r) {
        const float rl = 1.f / lrow[r];
#pragma unroll
        for (int dt = 0; dt < 4; ++dt)
            Cb[obase + (size_t)r * HDIM + dt * 16 + kcol] = f2bf(accO[dt][r] * rl);
    }
}

// ---------------------------------------------------------------------------
// ada-LayerNorm (unchanged)
// ---------------------------------------------------------------------------
template<int MODE, bool WRITE_BF>
__global__ __launch_bounds__(256)
void adaln_k(const float* __restrict__ a, const float* __restrict__ fo,
             const float* __restrict__ g, const float* __restrict__ vol,
             const float* __restrict__ lw, const float* __restrict__ lb,
             const float* __restrict__ gm, const float* __restrict__ bt,
             const float* __restrict__ vsw, const float* __restrict__ vsb,
             float* __restrict__ out, unsigned short* __restrict__ out_bf)
{
    const int tok = blockIdx.x;
    const int tid = threadIdx.x;
    const size_t base = (size_t)tok * HDIM + tid * 4;
    float v[4];
    {
        float4 va = *(const float4*)&a[base];
        if (MODE == 1) {
            float4 vf = *(const float4*)&fo[base];
            float4 vg = *(const float4*)&g[base];
            v[0] = va.x * (2.f - vg.x) + vf.x * vg.x;
            v[1] = va.y * (2.f - vg.y) + vf.y * vg.y;
            v[2] = va.z * (2.f - vg.z) + vf.z * vg.z;
            v[3] = va.w * (2.f - vg.w) + vf.w * vg.w;
        } else {
            v[0] = va.x; v[1] = va.y; v[2] = va.z; v[3] = va.w;
        }
    }
    float sum = v[0] + v[1] + v[2] + v[3];
    float sq  = v[0]*v[0] + v[1]*v[1] + v[2]*v[2] + v[3]*v[3];
#pragma unroll
    for (int off = 32; off > 0; off >>= 1) {
        sum += __shfl_down(sum, off);
        sq  += __shfl_down(sq, off);
    }
    __shared__ float ssum[4], ssq[4];
    const int wid = tid >> 6, lane = tid & 63;
    if (lane == 0) { ssum[wid] = sum; ssq[wid] = sq; }
    __syncthreads();
    const float tsum = ssum[0] + ssum[1] + ssum[2] + ssum[3];
    const float tsq  = ssq[0]  + ssq[1]  + ssq[2]  + ssq[3];
    const float mu   = tsum * (1.f / 1024.f);
    const float var  = tsq * (1.f / 1024.f) - mu * mu;
    const float rstd = rsqrtf(var + LNEPS);
    const float vsv  = 1.f / (1.f + __expf(-(vol[tok] * vsw[0] + vsb[0])));
    const float sca  = (1.f + vsv) * gm[0];
    const float off2 = bt[0];
    const float4 lwv = *(const float4*)&lw[tid * 4];
    const float4 lbv = *(const float4*)&lb[tid * 4];
    float r0 = ((v[0] - mu) * rstd * lwv.x + lbv.x) * sca + off2;
    float r1 = ((v[1] - mu) * rstd * lwv.y + lbv.y) * sca + off2;
    float r2 = ((v[2] - mu) * rstd * lwv.z + lbv.z) * sca + off2;
    float r3 = ((v[3] - mu) * rstd * lwv.w + lbv.w) * sca + off2;
    *(float4*)&out[base] = make_float4(r0, r1, r2, r3);
    if (WRITE_BF) {
        ushort4 ob;
        ob.x = f2bf(r0); ob.y = f2bf(r1); ob.z = f2bf(r2); ob.w = f2bf(r3);
        *(ushort4*)&out_bf[base] = ob;
    }
}

// ---------------------------------------------------------------------------
extern "C" void kernel_launch(void* const* d_in, const int* in_sizes, int n_in,
                              void* d_out, int out_size, void* d_ws, size_t ws_size,
                              hipStream_t stream)
{
    (void)in_sizes; (void)n_in; (void)out_size; (void)ws_size;
    const float* x    = (const float*)d_in[0];
    const float* vol  = (const float*)d_in[1];
    const float* Wq   = (const float*)d_in[2];  const float* bq  = (const float*)d_in[3];
    const float* Wk   = (const float*)d_in[4];  const float* bk  = (const float*)d_in[5];
    const float* Wv   = (const float*)d_in[6];  const float* bv  = (const float*)d_in[7];
    const float* Wo   = (const float*)d_in[8];  const float* bo  = (const float*)d_in[9];
    const float* ln1w = (const float*)d_in[10]; const float* ln1b = (const float*)d_in[11];
    const float* gm1  = (const float*)d_in[12]; const float* be1 = (const float*)d_in[13];
    const float* vs1w = (const float*)d_in[14]; const float* vs1b = (const float*)d_in[15];
    const float* fw1  = (const float*)d_in[16]; const float* fb1 = (const float*)d_in[17];
    const float* fw2  = (const float*)d_in[18]; const float* fb2 = (const float*)d_in[19];
    const float* gw1  = (const float*)d_in[20]; const float* gb1 = (const float*)d_in[21];
    const float* gw2  = (const float*)d_in[22]; const float* gb2 = (const float*)d_in[23];
    const float* ln2w = (const float*)d_in[24]; const float* ln2b = (const float*)d_in[25];
    const float* gm2  = (const float*)d_in[26]; const float* be2 = (const float*)d_in[27];
    const float* vs2w = (const float*)d_in[28]; const float* vs2b = (const float*)d_in[29];

    char* w = (char*)d_ws;
    auto MB = [](size_t v) { return v << 20; };
    unsigned short* wtqkv = (unsigned short*)(w + MB(0));   // 0-6
    unsigned short* wto   = (unsigned short*)(w + MB(6));
    unsigned short* wtf1  = (unsigned short*)(w + MB(8));
    unsigned short* wtf2  = (unsigned short*)(w + MB(16));
    unsigned short* wtg1  = (unsigned short*)(w + MB(24));
    unsigned short* wtg2  = (unsigned short*)(w + MB(25));
    unsigned short* xb   = (unsigned short*)(w + MB(26));   // 26-42
    unsigned short* qkvb = (unsigned short*)(w + MB(42));   // 42-90 [8192][3072]
    unsigned short* vtb  = (unsigned short*)(w + MB(90));   // 90-106
    unsigned short* cxb  = (unsigned short*)(w + MB(106));  // 106-122
    float*          ao   = (float*)(w + MB(122));           // 122-154
    float*          x1   = (float*)(w + MB(42));            // 42-74 (qkv dead)
    unsigned short* x1b  = (unsigned short*)(w + MB(74));   // 74-90
    unsigned short* hb   = (unsigned short*)(w + MB(90));   // 90-154
    float*          ffn  = (float*)(w + MB(154));           // 154-186
    unsigned short* ghb  = (unsigned short*)(w + MB(26));   // 26-34 (xb dead)
    float*          gg   = (float*)(w + MB(90));            // 90-122 (hb dead)
    float*          bqkv = (float*)(w + MB(186));           // 12 KB

    dim3 blk(256);
    dim3 tb(32, 8);
    transpose_cast4_k<<<dim3(32, 32, 4), tb, 0, stream>>>(Wq, Wk, Wv, Wo, wtqkv);
    transpose_cast_k<<<dim3(4096/32, 1024/32), tb, 0, stream>>>(fw1, wtf1, 1024, 4096);
    transpose_cast_k<<<dim3(1024/32, 4096/32), tb, 0, stream>>>(fw2, wtf2, 4096, 1024);
    transpose_cast_k<<<dim3(512/32, 1024/32),  tb, 0, stream>>>(gw1, wtg1, 1024, 512);
    transpose_cast_k<<<dim3(1024/32, 512/32),  tb, 0, stream>>>(gw2, wtg2, 512, 1024);
    cast_bf16_k<<<2048, blk, 0, stream>>>(x, xb, NTOK * HDIM / 4);
    concat3_k<<<12, blk, 0, stream>>>(bq, bk, bv, bqkv);

    const size_t SH128 = (128 + 128) * 256;   // 64 KiB
    const size_t SH256 = (256 + 256) * 256;   // 128 KiB
    gemm8_k<128, 128, ACT_NONE, false, true><<<dim3(24, 64), 512, SH128, stream>>>(
        xb, wtqkv, bqkv, nullptr, qkvb, NTOK, QKVSTR, HDIM);
    transpose_v_k<<<dim3(NSEQ / 64, NHEAD, NBATCH), blk, 0, stream>>>(qkvb + 2048, vtb);
    attn_k<<<dim3(2048), blk, 0, stream>>>(qkvb, vtb, cxb);
    gemm8_k<128, 128, ACT_NONE, true, false><<<dim3(8, 64), 512, SH128, stream>>>(
        cxb, wto, bo, x, ao, NTOK, HDIM, HDIM);
    adaln_k<0, true><<<dim3(NTOK), blk, 0, stream>>>(
        ao, nullptr, nullptr, vol, ln1w, ln1b, gm1, be1, vs1w, vs1b, x1, x1b);
    gemm8_k<256, 256, ACT_GELU, false, true><<<dim3(16, 32), 512, SH256, stream>>>(
        x1b, wtf1, fb1, nullptr, hb, NTOK, 4096, HDIM);
    gemm8_k<128, 128, ACT_NONE, false, false><<<dim3(8, 64), 512, SH128, stream>>>(
        hb, wtf2, fb2, nullptr, ffn, NTOK, HDIM, 4096);
    gemm8_k<128, 128, ACT_RELU, false, true><<<dim3(4, 64), 512, SH128, stream>>>(
        x1b, wtg1, gb1, nullptr, ghb, NTOK, 512, HDIM);
    gemm8_k<128, 128, ACT_SIG, false, false><<<dim3(8, 64), 512, SH128, stream>>>(
        ghb, wtg2, gb2, nullptr, gg, NTOK, HDIM, 512);
    adaln_k<1, false><<<dim3(NTOK), blk, 0, stream>>>(
        x1, ffn, gg, vol, ln2w, ln2b, gm2, be2, vs2w, vs2b, (float*)d_out, nullptr);
}

// Round 8
// 455.861 us; speedup vs baseline: 9.5578x; 1.1056x over previous
//
#include <hip/hip_runtime.h>
#include <hip/hip_bf16.h>
#include <math.h>

// EnhancedTransformerBlock on MI355X — Round 8: attn v3.
//  * 8 waves/block (128 q-rows) sharing K/V staging -> 3 blocks/CU, 24 waves/CU.
//  * per-lane partial softmax denominator (single end-of-loop reduce).
//  * lazy max: lane-local max guard vs mrow+8; full shuffle-reduce + rescale
//    only when triggered (first tile + rare max growth).
//  * GEMM (snake phases, counted vmcnt, XOR swizzle) unchanged from round 7.

#define HDIM 1024
#define NHEAD 16
#define DHEAD 64
#define NBATCH 8
#define NSEQ 1024
#define NTOK (NBATCH * NSEQ)   // 8192
#define QKVSTR 3072            // fused qkv row stride
#define LNEPS 1e-5f
#define LOG2E_8 0.180336880f   // log2(e)/8

using f32x4 = __attribute__((ext_vector_type(4))) float;
using s16x8 = __attribute__((ext_vector_type(8))) short;
using u16x8 = __attribute__((ext_vector_type(8))) unsigned short;

enum { ACT_NONE = 0, ACT_GELU = 1, ACT_RELU = 2, ACT_SIG = 3 };

__device__ inline float bf2f(unsigned short u) {
    union { unsigned u; float f; } t; t.u = ((unsigned)u) << 16; return t.f;
}
__device__ inline unsigned short f2bf(float f) {
    __hip_bfloat16 h = __float2bfloat16(f);
    return *reinterpret_cast<unsigned short*>(&h);
}
__device__ inline float gelu_f(float t) {
    const float u = t * (0.7978845608f + 0.0356774081f * t * t);
    const float e = __expf(2.f * u);
    const float th = 1.f - 2.f / (e + 1.f);
    return 0.5f * t * (1.f + th);
}

#define GLDS16(g, l) __builtin_amdgcn_global_load_lds( \
    (__attribute__((address_space(1))) void*)(g),      \
    (__attribute__((address_space(3))) void*)(l), 16, 0, 0)

// ---------------------------------------------------------------------------
__global__ __launch_bounds__(256)
void cast_bf16_k(const float* __restrict__ in, unsigned short* __restrict__ out, int n4)
{
    for (int i = blockIdx.x * 256 + threadIdx.x; i < n4; i += gridDim.x * 256) {
        float4 v = ((const float4*)in)[i];
        ushort4 o;
        o.x = f2bf(v.x); o.y = f2bf(v.y); o.z = f2bf(v.z); o.w = f2bf(v.w);
        ((ushort4*)out)[i] = o;
    }
}

// ---------------------------------------------------------------------------
__global__ __launch_bounds__(256)
void concat3_k(const float* __restrict__ a, const float* __restrict__ b,
               const float* __restrict__ c, float* __restrict__ o)
{
    int i = blockIdx.x * 256 + threadIdx.x;   // grid 12 -> 3072
    o[i] = i < 1024 ? a[i] : (i < 2048 ? b[i - 1024] : c[i - 2048]);
}

// ---------------------------------------------------------------------------
// W[K,N] fp32 -> Wt[N,K] bf16
// ---------------------------------------------------------------------------
__global__ __launch_bounds__(256)
void transpose_cast_k(const float* __restrict__ W, unsigned short* __restrict__ Wt,
                      int K, int N)
{
    __shared__ float tile[32][33];
    const int tx = threadIdx.x, ty = threadIdx.y;
    const int k0 = blockIdx.y * 32, n0 = blockIdx.x * 32;
#pragma unroll
    for (int r = 0; r < 32; r += 8)
        tile[ty + r][tx] = W[(size_t)(k0 + ty + r) * N + n0 + tx];
    __syncthreads();
#pragma unroll
    for (int r = 0; r < 32; r += 8)
        Wt[(size_t)(n0 + ty + r) * K + k0 + tx] = f2bf(tile[tx][ty + r]);
}

// 4 H x H weights in one launch (z selects)
__global__ __launch_bounds__(256)
void transpose_cast4_k(const float* __restrict__ W0, const float* __restrict__ W1,
                       const float* __restrict__ W2, const float* __restrict__ W3,
                       unsigned short* __restrict__ Wt)
{
    __shared__ float tile[32][33];
    const int z = blockIdx.z;
    const float* W = z == 0 ? W0 : z == 1 ? W1 : z == 2 ? W2 : W3;
    unsigned short* dst = Wt + (size_t)z * HDIM * HDIM;
    const int tx = threadIdx.x, ty = threadIdx.y;
    const int k0 = blockIdx.y * 32, n0 = blockIdx.x * 32;
#pragma unroll
    for (int r = 0; r < 32; r += 8)
        tile[ty + r][tx] = W[(size_t)(k0 + ty + r) * HDIM + n0 + tx];
    __syncthreads();
#pragma unroll
    for (int r = 0; r < 32; r += 8)
        dst[(size_t)(n0 + ty + r) * HDIM + k0 + tx] = f2bf(tile[tx][ty + r]);
}

// ---------------------------------------------------------------------------
// V (strided in fused qkv) -> Vt[(b*NHEAD+h)*64+d][s]
// ---------------------------------------------------------------------------
__global__ __launch_bounds__(256)
void transpose_v_k(const unsigned short* __restrict__ vb, unsigned short* __restrict__ vtb)
{
    __shared__ unsigned short t[64][72];
    const int tid = threadIdx.x;
    const int b = blockIdx.z, h = blockIdx.y;
    const int s0 = blockIdx.x * 64;
    {
        const int r = tid >> 3, c = (tid & 7) * 8;
        *(u16x8*)&t[r][c] =
            *(const u16x8*)&vb[((size_t)(b * NSEQ + s0 + r)) * QKVSTR + h * DHEAD + c];
        *(u16x8*)&t[r + 32][c] =
            *(const u16x8*)&vb[((size_t)(b * NSEQ + s0 + r + 32)) * QKVSTR + h * DHEAD + c];
    }
    __syncthreads();
    {
        const int d = tid & 63, sc = (tid >> 6) * 16;
        u16x8 o0, o1;
#pragma unroll
        for (int i = 0; i < 8; ++i) o0[i] = t[sc + i][d];
#pragma unroll
        for (int i = 0; i < 8; ++i) o1[i] = t[sc + 8 + i][d];
        unsigned short* dst = &vtb[((size_t)((b * NHEAD + h) * DHEAD + d)) * NSEQ + s0 + sc];
        *(u16x8*)dst = o0;
        *(u16x8*)(dst + 8) = o1;
    }
}

// ---------------------------------------------------------------------------
// Deep-pipelined bf16 MFMA GEMM (round-7, unchanged).
// ---------------------------------------------------------------------------
template<int BM, int BN, int ACT, bool HAS_ADD, bool OUT_BF>
__global__ __launch_bounds__(512, (BM == 128) ? 4 : 2)
void gemm8_k(const unsigned short* __restrict__ A, const unsigned short* __restrict__ Bt,
             const float* __restrict__ bias, const float* __restrict__ add,
             void* __restrict__ Cv, int M, int N, int K)
{
    extern __shared__ __align__(16) unsigned short lds[];
    constexpr int BK = 64;
    constexpr int WN = (BN == 256) ? 4 : 2;
    constexpr int WM = 8 / WN;
    constexpr int MREP = BM / (WM * 16);
    constexpr int NREP = BN / (WN * 16);
    constexpr int ASZ = BM * BK;
    constexpr int BSZ = BN * BK;
    constexpr int AR = BM / 64;
    constexpr int BR = BN / 64;
    constexpr int VM = AR + BR;
    constexpr int NPH = (BN == 256) ? 4 : 2;
    constexpr int MI_PER = MREP / 2;
    constexpr int NJ_PER = (BN == 256) ? 2 : 4;

    const int tid = threadIdx.x;
    const int lane = tid & 63;
    const int w = tid >> 6;
    const int wr = w / WN;
    const int wc = w % WN;
    const int m0 = blockIdx.y * BM;
    const int n0 = blockIdx.x * BN;
    const int fr = lane & 15;
    const int fo = lane >> 4;

    const int srow = tid >> 3;
    const int sslot = (tid & 7) ^ (srow & 7);
    const size_t a_base = (size_t)(m0 + srow) * K + sslot * 8;
    const size_t b_base = (size_t)(n0 + srow) * K + sslot * 8;

    f32x4 acc[MREP][NREP] = {};

    auto stage = [&](int t) {
        const int buf = t & 1;
        unsigned short* ad = lds + buf * ASZ + w * 512;
        unsigned short* bd = lds + 2 * ASZ + buf * BSZ + w * 512;
        const unsigned short* as_ = A + a_base + (size_t)t * BK;
        const unsigned short* bs_ = Bt + b_base + (size_t)t * BK;
#pragma unroll
        for (int j = 0; j < AR; ++j)
            GLDS16(as_ + (size_t)j * 64 * K, ad + j * 4096);
#pragma unroll
        for (int j = 0; j < BR; ++j)
            GLDS16(bs_ + (size_t)j * 64 * K, bd + j * 4096);
    };

    const int NT = K / BK;
    stage(0);

    for (int t = 0; t < NT; ++t) {
        if (t + 1 < NT) {
            stage(t + 1);
            asm volatile("s_waitcnt vmcnt(%0)" :: "i"(VM) : "memory");
        } else {
            asm volatile("s_waitcnt vmcnt(0)" ::: "memory");
        }
        __builtin_amdgcn_s_barrier();

        const char* Ab = (const char*)(lds + (t & 1) * ASZ);
        const char* Bb = (const char*)(lds + 2 * ASZ + (t & 1) * BSZ);

        s16x8 af[MI_PER][2], bfr[NJ_PER][2];
#pragma unroll
        for (int ph = 0; ph < NPH; ++ph) {
            const int mh = (BN == 256) ? ((ph == 1 || ph == 2) ? 1 : 0) : ph;
            const int nh = (BN == 256) ? (ph >> 1) : 0;
            const bool la = (BN != 256) || (ph != 2);
            const bool lb = (BN == 256) ? ((ph & 1) == 0) : (ph == 0);
            if (la) {
#pragma unroll
                for (int i = 0; i < MI_PER; ++i) {
                    const int row = wr * (BM / WM) + (mh * MI_PER + i) * 16 + fr;
                    const int sw = (row & 7) << 4;
#pragma unroll
                    for (int kk = 0; kk < 2; ++kk)
                        af[i][kk] = *(const s16x8*)(Ab + row * 128 + ((kk * 64 + fo * 16) ^ sw));
                }
            }
            if (lb) {
#pragma unroll
                for (int j = 0; j < NJ_PER; ++j) {
                    const int row = wc * 64 + (nh * NJ_PER + j) * 16 + fr;
                    const int sw = (row & 7) << 4;
#pragma unroll
                    for (int kk = 0; kk < 2; ++kk)
                        bfr[j][kk] = *(const s16x8*)(Bb + row * 128 + ((kk * 64 + fo * 16) ^ sw));
                }
            }
            __builtin_amdgcn_s_setprio(1);
#pragma unroll
            for (int i = 0; i < MI_PER; ++i)
#pragma unroll
                for (int j = 0; j < NJ_PER; ++j)
#pragma unroll
                    for (int kk = 0; kk < 2; ++kk)
                        acc[mh * MI_PER + i][nh * NJ_PER + j] =
                            __builtin_amdgcn_mfma_f32_16x16x32_bf16(
                                af[i][kk], bfr[j][kk],
                                acc[mh * MI_PER + i][nh * NJ_PER + j], 0, 0, 0);
            __builtin_amdgcn_s_setprio(0);
        }
        asm volatile("s_waitcnt lgkmcnt(0)" ::: "memory");
        __builtin_amdgcn_sched_barrier(0);
        __builtin_amdgcn_s_barrier();
    }

    float bv[NREP];
#pragma unroll
    for (int j = 0; j < NREP; ++j)
        bv[j] = bias[n0 + wc * 64 + j * 16 + fr];
#pragma unroll
    for (int i = 0; i < MREP; ++i) {
#pragma unroll
        for (int j = 0; j < NREP; ++j) {
            const int gn = n0 + wc * 64 + j * 16 + fr;
#pragma unroll
            for (int r = 0; r < 4; ++r) {
                const int gm = m0 + wr * (BM / WM) + i * 16 + fo * 4 + r;
                float t = acc[i][j][r] + bv[j];
                if (HAS_ADD) t += add[(size_t)gm * N + gn];
                if (ACT == ACT_GELU)      t = gelu_f(t);
                else if (ACT == ACT_RELU) t = fmaxf(t, 0.f);
                else if (ACT == ACT_SIG)  t = 1.f / (1.f + __expf(-t));
                if (OUT_BF) ((unsigned short*)Cv)[(size_t)gm * N + gn] = f2bf(t);
                else        ((float*)Cv)[(size_t)gm * N + gn] = t;
            }
        }
    }
}

// ---------------------------------------------------------------------------
// MFMA flash attention v3. Block = 512 thr (8 waves x 16 q-rows = 128 q-rows),
// one K/V staging shared by all waves. XCD-clustered decode (1024 = 128 bh x 8 qt).
// Per-lane partial softmax denominator; lazy max guard (full reduce+rescale only
// when lane-local max exceeds mrow+8).
// ---------------------------------------------------------------------------
__global__ __launch_bounds__(512, 6)
void attn_k(const unsigned short* __restrict__ QKVb, const unsigned short* __restrict__ Vtb,
            unsigned short* __restrict__ Cb)
{
    __shared__ alignas(16) unsigned short Ks[2][64 * 64];
    __shared__ alignas(16) unsigned short Vs[2][64 * 64];
    __shared__ alignas(16) unsigned short Ps[8][16 * 72];

    const int tid = threadIdx.x;
    const int lane = tid & 63;
    const int wid = tid >> 6;          // 0..7
    const int L = blockIdx.x;          // 1024 = 128 bh * 8 qt
    const int xcd = L & 7, s = L >> 3;
    const int bh = xcd + ((s >> 3) << 3);
    const int qt = s & 7;
    const int b = bh >> 4, h = bh & 15;
    const int q0 = qt * 128 + wid * 16;

    const int kcol = lane & 15;
    const int kofs = (lane >> 4) * 8;
    const size_t qoff = ((size_t)(b * NSEQ + q0 + kcol)) * QKVSTR + h * DHEAD + kofs;
    const s16x8 qf0 = *(const s16x8*)(QKVb + qoff);
    const s16x8 qf1 = *(const s16x8*)(QKVb + qoff + 32);

    f32x4 accO[4] = {};
    float mrow[4] = {-1e30f, -1e30f, -1e30f, -1e30f};
    float lsum[4] = {0.f, 0.f, 0.f, 0.f};      // per-lane partial denominator

    const int lr = lane >> 3;
    const int swz8 = (((lane & 7) ^ lr)) * 8;
    const size_t kbase  = ((size_t)(b * NSEQ)) * QKVSTR + HDIM + h * DHEAD;
    const size_t vtbase = ((size_t)(bh * DHEAD)) * NSEQ;

    unsigned short* const pw = &Ps[wid][0];
    const int prow = (lane >> 4) * 4;

    // per wave: 1 K-load + 1 V-load covering 8 rows (64 lanes x 16B)
    auto stage = [&](int kt, int buf) {
        const int rowb = wid * 8;
        GLDS16(QKVb + kbase + (size_t)(kt * 64 + rowb + lr) * QKVSTR + swz8,
               Ks[buf] + rowb * 64);
        GLDS16(Vtb + vtbase + (size_t)(rowb + lr) * NSEQ + kt * 64 + swz8,
               Vs[buf] + rowb * 64);
    };

    stage(0, 0);
    asm volatile("s_waitcnt vmcnt(0)" ::: "memory");
    __syncthreads();

    for (int kt = 0; kt < NSEQ / 64; ++kt) {
        const int cur = kt & 1;
        if (kt + 1 < NSEQ / 64) stage(kt + 1, cur ^ 1);

        // ---- QK^T
        f32x4 sa[4];
#pragma unroll
        for (int jt = 0; jt < 4; ++jt) {
            const int kr = jt * 16 + kcol;
            const unsigned swz = ((unsigned)(kr & 7)) << 4;
            const s16x8 kf0 = *(const s16x8*)((const char*)Ks[cur] + kr * 128 + ((kofs * 2) ^ swz));
            const s16x8 kf1 = *(const s16x8*)((const char*)Ks[cur] + kr * 128 + ((64 + kofs * 2) ^ swz));
            f32x4 t = {};
            t = __builtin_amdgcn_mfma_f32_16x16x32_bf16(qf0, kf0, t, 0, 0, 0);
            t = __builtin_amdgcn_mfma_f32_16x16x32_bf16(qf1, kf1, t, 0, 0, 0);
            sa[jt] = t * LOG2E_8;
        }

        // ---- lazy-max online softmax
        float lmax[4];
#pragma unroll
        for (int r = 0; r < 4; ++r)
            lmax[r] = fmaxf(fmaxf(sa[0][r], sa[1][r]), fmaxf(sa[2][r], sa[3][r]));
        const float guard = fmaxf(fmaxf(lmax[0] - mrow[0], lmax[1] - mrow[1]),
                                  fmaxf(lmax[2] - mrow[2], lmax[3] - mrow[3]));
        if (!__all(guard <= 8.f)) {
#pragma unroll
            for (int r = 0; r < 4; ++r) {
                float m = lmax[r];
                m = fmaxf(m, __shfl_xor(m, 1));
                m = fmaxf(m, __shfl_xor(m, 2));
                m = fmaxf(m, __shfl_xor(m, 4));
                m = fmaxf(m, __shfl_xor(m, 8));
                const float mn = fmaxf(mrow[r], m);
                const float corr = exp2f(mrow[r] - mn);
                mrow[r] = mn;
                lsum[r] *= corr;
#pragma unroll
                for (int dt = 0; dt < 4; ++dt) accO[dt][r] *= corr;
            }
        }
#pragma unroll
        for (int r = 0; r < 4; ++r) {
#pragma unroll
            for (int jt = 0; jt < 4; ++jt) {
                const float p = exp2f(sa[jt][r] - mrow[r]);
                pw[(prow + r) * 72 + jt * 16 + kcol] = f2bf(p);
                lsum[r] += p;
            }
        }

        // ---- PV
#pragma unroll
        for (int kc = 0; kc < 2; ++kc) {
            const s16x8 pa = *(const s16x8*)(pw + kcol * 72 + kc * 32 + kofs);
#pragma unroll
            for (int dt = 0; dt < 4; ++dt) {
                const int dr = dt * 16 + kcol;
                const unsigned swz = ((unsigned)(dr & 7)) << 4;
                const s16x8 vf = *(const s16x8*)((const char*)Vs[cur] + dr * 128 +
                                                 ((kc * 64 + kofs * 2) ^ swz));
                accO[dt] = __builtin_amdgcn_mfma_f32_16x16x32_bf16(pa, vf, accO[dt], 0, 0, 0);
            }
        }

        if (kt + 1 < NSEQ / 64) asm volatile("s_waitcnt vmcnt(0)" ::: "memory");
        __builtin_amdgcn_s_barrier();
    }

    // ---- single end-of-loop denominator reduce (16-lane groups)
#pragma unroll
    for (int r = 0; r < 4; ++r) {
        lsum[r] += __shfl_xor(lsum[r], 1);
        lsum[r] += __shfl_xor(lsum[r], 2);
        lsum[r] += __shfl_xor(lsum[r], 4);
        lsum[r] += __shfl_xor(lsum[r], 8);
    }

    const size_t obase = ((size_t)(b * NSEQ + q0 + prow)) * HDIM + h * DHEAD;
#pragma unroll
    for (int r = 0; r < 4; ++r) {
        const float rl = 1.f / lsum[r];
#pragma unroll
        for (int dt = 0; dt < 4; ++dt)
            Cb[obase + (size_t)r * HDIM + dt * 16 + kcol] = f2bf(accO[dt][r] * rl);
    }
}

// ---------------------------------------------------------------------------
// ada-LayerNorm (unchanged)
// ---------------------------------------------------------------------------
template<int MODE, bool WRITE_BF>
__global__ __launch_bounds__(256)
void adaln_k(const float* __restrict__ a, const float* __restrict__ fo,
             const float* __restrict__ g, const float* __restrict__ vol,
             const float* __restrict__ lw, const float* __restrict__ lb,
             const float* __restrict__ gm, const float* __restrict__ bt,
             const float* __restrict__ vsw, const float* __restrict__ vsb,
             float* __restrict__ out, unsigned short* __restrict__ out_bf)
{
    const int tok = blockIdx.x;
    const int tid = threadIdx.x;
    const size_t base = (size_t)tok * HDIM + tid * 4;
    float v[4];
    {
        float4 va = *(const float4*)&a[base];
        if (MODE == 1) {
            float4 vf = *(const float4*)&fo[base];
            float4 vg = *(const float4*)&g[base];
            v[0] = va.x * (2.f - vg.x) + vf.x * vg.x;
            v[1] = va.y * (2.f - vg.y) + vf.y * vg.y;
            v[2] = va.z * (2.f - vg.z) + vf.z * vg.z;
            v[3] = va.w * (2.f - vg.w) + vf.w * vg.w;
        } else {
            v[0] = va.x; v[1] = va.y; v[2] = va.z; v[3] = va.w;
        }
    }
    float sum = v[0] + v[1] + v[2] + v[3];
    float sq  = v[0]*v[0] + v[1]*v[1] + v[2]*v[2] + v[3]*v[3];
#pragma unroll
    for (int off = 32; off > 0; off >>= 1) {
        sum += __shfl_down(sum, off);
        sq  += __shfl_down(sq, off);
    }
    __shared__ float ssum[4], ssq[4];
    const int wid = tid >> 6, lane = tid & 63;
    if (lane == 0) { ssum[wid] = sum; ssq[wid] = sq; }
    __syncthreads();
    const float tsum = ssum[0] + ssum[1] + ssum[2] + ssum[3];
    const float tsq  = ssq[0]  + ssq[1]  + ssq[2]  + ssq[3];
    const float mu   = tsum * (1.f / 1024.f);
    const float var  = tsq * (1.f / 1024.f) - mu * mu;
    const float rstd = rsqrtf(var + LNEPS);
    const float vsv  = 1.f / (1.f + __expf(-(vol[tok] * vsw[0] + vsb[0])));
    const float sca  = (1.f + vsv) * gm[0];
    const float off2 = bt[0];
    const float4 lwv = *(const float4*)&lw[tid * 4];
    const float4 lbv = *(const float4*)&lb[tid * 4];
    float r0 = ((v[0] - mu) * rstd * lwv.x + lbv.x) * sca + off2;
    float r1 = ((v[1] - mu) * rstd * lwv.y + lbv.y) * sca + off2;
    float r2 = ((v[2] - mu) * rstd * lwv.z + lbv.z) * sca + off2;
    float r3 = ((v[3] - mu) * rstd * lwv.w + lbv.w) * sca + off2;
    *(float4*)&out[base] = make_float4(r0, r1, r2, r3);
    if (WRITE_BF) {
        ushort4 ob;
        ob.x = f2bf(r0); ob.y = f2bf(r1); ob.z = f2bf(r2); ob.w = f2bf(r3);
        *(ushort4*)&out_bf[base] = ob;
    }
}

// ---------------------------------------------------------------------------
extern "C" void kernel_launch(void* const* d_in, const int* in_sizes, int n_in,
                              void* d_out, int out_size, void* d_ws, size_t ws_size,
                              hipStream_t stream)
{
    (void)in_sizes; (void)n_in; (void)out_size; (void)ws_size;
    const float* x    = (const float*)d_in[0];
    const float* vol  = (const float*)d_in[1];
    const float* Wq   = (const float*)d_in[2];  const float* bq  = (const float*)d_in[3];
    const float* Wk   = (const float*)d_in[4];  const float* bk  = (const float*)d_in[5];
    const float* Wv   = (const float*)d_in[6];  const float* bv  = (const float*)d_in[7];
    const float* Wo   = (const float*)d_in[8];  const float* bo  = (const float*)d_in[9];
    const float* ln1w = (const float*)d_in[10]; const float* ln1b = (const float*)d_in[11];
    const float* gm1  = (const float*)d_in[12]; const float* be1 = (const float*)d_in[13];
    const float* vs1w = (const float*)d_in[14]; const float* vs1b = (const float*)d_in[15];
    const float* fw1  = (const float*)d_in[16]; const float* fb1 = (const float*)d_in[17];
    const float* fw2  = (const float*)d_in[18]; const float* fb2 = (const float*)d_in[19];
    const float* gw1  = (const float*)d_in[20]; const float* gb1 = (const float*)d_in[21];
    const float* gw2  = (const float*)d_in[22]; const float* gb2 = (const float*)d_in[23];
    const float* ln2w = (const float*)d_in[24]; const float* ln2b = (const float*)d_in[25];
    const float* gm2  = (const float*)d_in[26]; const float* be2 = (const float*)d_in[27];
    const float* vs2w = (const float*)d_in[28]; const float* vs2b = (const float*)d_in[29];

    char* w = (char*)d_ws;
    auto MB = [](size_t v) { return v << 20; };
    unsigned short* wtqkv = (unsigned short*)(w + MB(0));   // 0-6
    unsigned short* wto   = (unsigned short*)(w + MB(6));
    unsigned short* wtf1  = (unsigned short*)(w + MB(8));
    unsigned short* wtf2  = (unsigned short*)(w + MB(16));
    unsigned short* wtg1  = (unsigned short*)(w + MB(24));
    unsigned short* wtg2  = (unsigned short*)(w + MB(25));
    unsigned short* xb   = (unsigned short*)(w + MB(26));   // 26-42
    unsigned short* qkvb = (unsigned short*)(w + MB(42));   // 42-90 [8192][3072]
    unsigned short* vtb  = (unsigned short*)(w + MB(90));   // 90-106
    unsigned short* cxb  = (unsigned short*)(w + MB(106));  // 106-122
    float*          ao   = (float*)(w + MB(122));           // 122-154
    float*          x1   = (float*)(w + MB(42));            // 42-74 (qkv dead)
    unsigned short* x1b  = (unsigned short*)(w + MB(74));   // 74-90
    unsigned short* hb   = (unsigned short*)(w + MB(90));   // 90-154
    float*          ffn  = (float*)(w + MB(154));           // 154-186
    unsigned short* ghb  = (unsigned short*)(w + MB(26));   // 26-34 (xb dead)
    float*          gg   = (float*)(w + MB(90));            // 90-122 (hb dead)
    float*          bqkv = (float*)(w + MB(186));           // 12 KB

    dim3 blk(256);
    dim3 tb(32, 8);
    transpose_cast4_k<<<dim3(32, 32, 4), tb, 0, stream>>>(Wq, Wk, Wv, Wo, wtqkv);
    transpose_cast_k<<<dim3(4096/32, 1024/32), tb, 0, stream>>>(fw1, wtf1, 1024, 4096);
    transpose_cast_k<<<dim3(1024/32, 4096/32), tb, 0, stream>>>(fw2, wtf2, 4096, 1024);
    transpose_cast_k<<<dim3(512/32, 1024/32),  tb, 0, stream>>>(gw1, wtg1, 1024, 512);
    transpose_cast_k<<<dim3(1024/32, 512/32),  tb, 0, stream>>>(gw2, wtg2, 512, 1024);
    cast_bf16_k<<<2048, blk, 0, stream>>>(x, xb, NTOK * HDIM / 4);
    concat3_k<<<12, blk, 0, stream>>>(bq, bk, bv, bqkv);

    const size_t SH128 = (128 + 128) * 256;   // 64 KiB
    const size_t SH256 = (256 + 256) * 256;   // 128 KiB
    gemm8_k<128, 128, ACT_NONE, false, true><<<dim3(24, 64), 512, SH128, stream>>>(
        xb, wtqkv, bqkv, nullptr, qkvb, NTOK, QKVSTR, HDIM);
    transpose_v_k<<<dim3(NSEQ / 64, NHEAD, NBATCH), blk, 0, stream>>>(qkvb + 2048, vtb);
    attn_k<<<dim3(1024), 512, 0, stream>>>(qkvb, vtb, cxb);
    gemm8_k<128, 128, ACT_NONE, true, false><<<dim3(8, 64), 512, SH128, stream>>>(
        cxb, wto, bo, x, ao, NTOK, HDIM, HDIM);
    adaln_k<0, true><<<dim3(NTOK), blk, 0, stream>>>(
        ao, nullptr, nullptr, vol, ln1w, ln1b, gm1, be1, vs1w, vs1b, x1, x1b);
    gemm8_k<256, 256, ACT_GELU, false, true><<<dim3(16, 32), 512, SH256, stream>>>(
        x1b, wtf1, fb1, nullptr, hb, NTOK, 4096, HDIM);
    gemm8_k<128, 128, ACT_NONE, false, false><<<dim3(8, 64), 512, SH128, stream>>>(
        hb, wtf2, fb2, nullptr, ffn, NTOK, HDIM, 4096);
    gemm8_k<128, 128, ACT_RELU, false, true><<<dim3(4, 64), 512, SH128, stream>>>(
        x1b, wtg1, gb1, nullptr, ghb, NTOK, 512, HDIM);
    gemm8_k<128, 128, ACT_SIG, false, false><<<dim3(8, 64), 512, SH128, stream>>>(
        ghb, wtg2, gb2, nullptr, gg, NTOK, HDIM, 512);
    adaln_k<1, false><<<dim3(NTOK), blk, 0, stream>>>(
        x1, ffn, gg, vol, ln2w, ln2b, gm2, be2, vs2w, vs2b, (float*)d_out, nullptr);
}